// Round 3
// baseline (284.206 us; speedup 1.0000x reference)
//
#include <hip/hip_runtime.h>

// LnnDynamics, role-per-block + LDS-weight version (v4):
//   role 0 (m): M-MLP fwd + JVP along qd -> Ms[21] (symmetrized), tc[6]
//   role 1 (u): U-MLP fwd + checkpointed reverse-mode -> tau_pot[6]
//   role 2 (d): D-MLP fwd -> tau_d[6]
//   combine:   r = tau@A - tc - tp - td ; solve Msym y = r
// v3 -> v4: ONLY change is padding the static LDS block 35 KB -> 56 KB.
// At 35 KB the AMDGPU backend sees 4 workgroups/CU possible -> targets
// 4 waves/SIMD -> caps VGPRs at 128 and SPILLS (v3: VGPR_Count=128,
// WRITE_SIZE=289MB scratch, 252us) even though launch_bounds(256,2)
// allows 256. Padding LDS to 57344 B (>160KB/3) makes the LDS-implied
// occupancy 2 blocks/CU = 2 waves/SIMD, so the allocator's budget
// becomes 256 VGPRs and the ~190-reg working set fits with no spill.
// Scratch sc is SoA: sc[field*B + b], fields 0-20 Ms, 21-26 tc, 27-32 tp, 33-38 td.

#define NQ 6
#define HID 32
#define NHID 4  // NL-1

// workspace float offsets (transposed weights, built by prep_kernel)
#define MW0T 0
#define UW0T 192
#define DW0T 384
#define MWHT 576
#define UWHT (576 + 4096)
#define DWHT (576 + 8192)
#define MWOT (576 + 12288)
#define DWOT (MWOT + 1152)
#define UWOT (DWOT + 1152)
#define SC_BASE 16384  // per-element scratch starts here (floats)

// LDS layout (floats):
//  role m/d: [0:192) W0t | [192:4288) Wht | [4288:5440) Wot
//            [5440:5472) b0 | [5472:5600) bh | [5600:5636) bo
//  role u:   [0:192) W0t | [192:4288) Wht | [4288:8384) Wh-original
//            [8384:8416) Wo | [8416:8608) W0-original
//            [8608:8640) b0 | [8640:8768) bh
#define LDS_FLOATS 8768
// padded to force 2 blocks/CU (57344 B > 163840/3) -> allocator targets
// 2 waves/SIMD -> 256-VGPR budget -> no spill
#define LDS_PAD_FLOATS 14336

__global__ void prep_kernel(const float* __restrict__ mW0, const float* __restrict__ mWh,
                            const float* __restrict__ mWo, const float* __restrict__ uW0,
                            const float* __restrict__ uWh, const float* __restrict__ uWo,
                            const float* __restrict__ dW0, const float* __restrict__ dWh,
                            const float* __restrict__ dWo, float* __restrict__ ws) {
  int t = blockIdx.x * blockDim.x + threadIdx.x;
  if (t < 192) {  // W0t[j*6+k] = W0[k*32+j]
    int j = t / 6, k = t % 6;
    ws[MW0T + t] = mW0[k * HID + j];
    ws[UW0T + t] = uW0[k * HID + j];
    ws[DW0T + t] = dW0[k * HID + j];
  }
  if (t < 4096) {  // Wht[(l*32+j)*32+k] = Wh[(l*32+k)*32+j]
    int l = t >> 10, j = (t >> 5) & 31, k = t & 31;
    int src = l * 1024 + k * 32 + j;
    ws[MWHT + t] = mWh[src];
    ws[UWHT + t] = uWh[src];
    ws[DWHT + t] = dWh[src];
  }
  if (t < 1152) {  // Wot[o*32+k] = Wo[k*36+o]
    int o = t / 32, k = t % 32;
    ws[MWOT + t] = mWo[k * 36 + o];
    ws[DWOT + t] = dWo[k * 36 + o];
  }
  if (t < 32) ws[UWOT + t] = uWo[t];
}

__device__ __forceinline__ float sp1(float z) {
  return fmaxf(z, 0.f) + __logf(1.f + __expf(-fabsf(z)));
}
__device__ __forceinline__ void sp_sig(float z, float& hs, float& sg) {
  float e = __expf(-fabsf(z));
  float d = __builtin_amdgcn_rcpf(1.f + e);
  hs = fmaxf(z, 0.f) + __logf(1.f + e);
  sg = (z >= 0.f ? 1.f : e) * d;
}
// h = softplus(z) >= 0  =>  sigmoid(z) = 1 - exp(-h)
__device__ __forceinline__ float sig_h(float h) { return 1.f - __expf(-h); }

// block-cooperative copies into LDS (256 threads)
__device__ __forceinline__ void cpy4(float* __restrict__ dst, const float* __restrict__ src,
                                     int n4, int t) {
  const float4* s = (const float4*)src;
  float4* d = (float4*)dst;
  for (int i = t; i < n4; i += 256) d[i] = s[i];
}
__device__ __forceinline__ void cpys(float* __restrict__ dst, const float* __restrict__ src, int n,
                                     int t) {
  for (int i = t; i < n; i += 256) dst[i] = src[i];
}

// m-role layer, two-pass (keeps only h + tin + tout live):
//   pass A: tout_j = zh_j = h . Wt_j + b_j
//   pass B: zt_j = tin . Wt_j ; h_j = softplus(zh_j) ; tout_j = zt_j * sigmoid(zh_j)
__device__ __forceinline__ void m_layer(const float* __restrict__ Wb, const float* __restrict__ bh,
                                        float* __restrict__ h, const float* __restrict__ tin,
                                        float* __restrict__ tout) {
#pragma unroll
  for (int j = 0; j < 32; j++) {
    const float* r = Wb + j * 32;
    float z = bh[j];
#pragma unroll
    for (int k = 0; k < 32; k++) z += h[k] * r[k];
    tout[j] = z;
  }
#pragma unroll
  for (int j = 0; j < 32; j++) {
    const float* r = Wb + j * 32;
    float z = 0.f;
#pragma unroll
    for (int k = 0; k < 32; k++) z += tin[k] * r[k];
    float hs, sg;
    sp_sig(tout[j], hs, sg);
    h[j] = hs;
    tout[j] = z * sg;
  }
}

// plain forward layer: hout = softplus(hin @ Wt + b)
__device__ __forceinline__ void fwd_layer(const float* __restrict__ Wb,
                                          const float* __restrict__ bh,
                                          const float* __restrict__ hin, float* __restrict__ hout) {
#pragma unroll
  for (int j = 0; j < 32; j++) {
    const float* r = Wb + j * 32;
    float z = bh[j];
#pragma unroll
    for (int k = 0; k < 32; k++) z += hin[k] * r[k];
    hout[j] = sp1(z);
  }
}

// backward matvec vs ORIGINAL-layout Wh rows: gout[k] = sum_j Wh[k][j] * gin[j]
__device__ __forceinline__ void bwd_mv(const float* __restrict__ Worig,
                                       const float* __restrict__ gin, float* __restrict__ gout) {
#pragma unroll
  for (int k = 0; k < 32; k++) {
    const float* r = Worig + k * 32;
    float s = 0.f;
#pragma unroll
    for (int j = 0; j < 32; j++) s += r[j] * gin[j];
    gout[k] = s;
  }
}

__global__ __launch_bounds__(256, 2) void roles3_lds_kernel(
    const float* __restrict__ in, const float* __restrict__ ws, const float* __restrict__ m_b0,
    const float* __restrict__ m_bh, const float* __restrict__ m_bo, const float* __restrict__ u_W0,
    const float* __restrict__ u_b0, const float* __restrict__ u_Wh, const float* __restrict__ u_bh,
    const float* __restrict__ u_Wo, const float* __restrict__ d_b0, const float* __restrict__ d_bh,
    const float* __restrict__ d_bo, float* __restrict__ sc, int B) {
  __shared__ __align__(16) float W[LDS_PAD_FLOATS];
  const int role = blockIdx.x % 3;
  const int t = threadIdx.x;

  // ---- stage role weights + biases into LDS ----
  if (role == 0) {
    cpy4(W, ws + MW0T, 48, t);
    cpy4(W + 192, ws + MWHT, 1024, t);
    cpy4(W + 4288, ws + MWOT, 288, t);
    cpys(W + 5440, m_b0, 32, t);
    cpys(W + 5472, m_bh, 128, t);
    cpys(W + 5600, m_bo, 36, t);
  } else if (role == 1) {
    cpy4(W, ws + UW0T, 48, t);
    cpy4(W + 192, ws + UWHT, 1024, t);
    cpy4(W + 4288, u_Wh, 1024, t);  // original layout for bwd
    cpy4(W + 8384, u_Wo, 8, t);
    cpy4(W + 8416, u_W0, 48, t);  // original layout for final grad
    cpys(W + 8608, u_b0, 32, t);
    cpys(W + 8640, u_bh, 128, t);
  } else {
    cpy4(W, ws + DW0T, 48, t);
    cpy4(W + 192, ws + DWHT, 1024, t);
    cpy4(W + 4288, ws + DWOT, 288, t);
    cpys(W + 5440, d_b0, 32, t);
    cpys(W + 5472, d_bh, 128, t);
    cpys(W + 5600, d_bo, 36, t);
  }
  __syncthreads();

  const int e = (blockIdx.x / 3) * 256 + t;
  if (e >= B) return;
  const float* ip = in + (long)e * 18;
  const long Bl = B;

  float x[6];
#pragma unroll
  for (int i = 0; i < 6; i++) x[i] = ip[i];

  if (role == 0) {
    // ================= m: fwd + JVP =================
    const float* w0 = W;
    const float* wh = W + 192;
    const float* wo = W + 4288;
    const float* b0 = W + 5440;
    const float* bh = W + 5472;
    const float* bo = W + 5600;
    float xd[6];
#pragma unroll
    for (int i = 0; i < 6; i++) xd[i] = ip[6 + i];
    float h[32], tv[32], zn[32];
#pragma unroll
    for (int j = 0; j < 32; j++) {
      const float* r = w0 + j * 6;
      float zh = b0[j], zt = 0.f;
#pragma unroll
      for (int k = 0; k < 6; k++) {
        zh += x[k] * r[k];
        zt += xd[k] * r[k];
      }
      float hs, sg;
      sp_sig(zh, hs, sg);
      h[j] = hs;
      tv[j] = zt * sg;
    }
    m_layer(wh + 0 * 1024, bh + 0, h, tv, zn);
    m_layer(wh + 1 * 1024, bh + 32, h, zn, tv);
    m_layer(wh + 2 * 1024, bh + 64, h, tv, zn);
    m_layer(wh + 3 * 1024, bh + 96, h, zn, tv);
    // symmetrized output, pairwise
    float Ms[21], tc[6] = {0, 0, 0, 0, 0, 0};
    int idx = 0;
#pragma unroll
    for (int i = 0; i < 6; i++)
#pragma unroll
      for (int j = i; j < 6; j++) {
        const float* r = wo + (i * 6 + j) * 32;
        float v = bo[i * 6 + j], w = 0.f;
#pragma unroll
        for (int k = 0; k < 32; k++) {
          v += h[k] * r[k];
          w += tv[k] * r[k];
        }
        if (i != j) {
          const float* r2 = wo + (j * 6 + i) * 32;
          float v2 = bo[j * 6 + i], w2 = 0.f;
#pragma unroll
          for (int k = 0; k < 32; k++) {
            v2 += h[k] * r2[k];
            w2 += tv[k] * r2[k];
          }
          v = 0.5f * (v + v2);
          w = 0.5f * (w + w2);
        }
        Ms[idx] = v;
        tc[i] += w * xd[j];
        if (j != i) tc[j] += w * xd[i];
        idx++;
      }
#pragma unroll
    for (int f = 0; f < 21; f++) sc[f * Bl + e] = Ms[f];
#pragma unroll
    for (int i = 0; i < 6; i++) sc[(21 + i) * Bl + e] = tc[i];
  } else if (role == 1) {
    // ================= u: fwd + checkpointed bwd =================
    const float* w0 = W;
    const float* wh = W + 192;    // transposed (fwd)
    const float* whO = W + 4288;  // original (bwd)
    const float* uwo = W + 8384;
    const float* uw0O = W + 8416;
    const float* b0 = W + 8608;
    const float* bh = W + 8640;
    float hb[32], hd[32], s[32], r2[32];
    // ha -> s
#pragma unroll
    for (int j = 0; j < 32; j++) {
      const float* r = w0 + j * 6;
      float z = b0[j];
#pragma unroll
      for (int k = 0; k < 6; k++) z += x[k] * r[k];
      s[j] = sp1(z);
    }
    fwd_layer(wh + 0 * 1024, bh + 0, s, hb);   // hb (checkpoint)
    fwd_layer(wh + 1 * 1024, bh + 32, hb, s);  // hc (dropped, recomputed later)
    fwd_layer(wh + 2 * 1024, bh + 64, s, hd);  // hd (checkpoint)
    fwd_layer(wh + 3 * 1024, bh + 96, hd, s);  // he
    // g = Wo * sig(he), in place in s
#pragma unroll
    for (int j = 0; j < 32; j++) s[j] = uwo[j] * sig_h(s[j]);
    bwd_mv(whO + 3 * 1024, s, r2);
#pragma unroll
    for (int j = 0; j < 32; j++) s[j] = r2[j] * sig_h(hd[j]);  // hd dead
    bwd_mv(whO + 2 * 1024, s, hd);                             // gn -> hd
    fwd_layer(wh + 1 * 1024, bh + 32, hb, s);                  // recompute hc -> s
#pragma unroll
    for (int j = 0; j < 32; j++) r2[j] = hd[j] * sig_h(s[j]);
    bwd_mv(whO + 1 * 1024, r2, s);
#pragma unroll
    for (int j = 0; j < 32; j++) r2[j] = s[j] * sig_h(hb[j]);  // hb dead
    bwd_mv(whO + 0 * 1024, r2, hb);
    // recompute ha -> s
#pragma unroll
    for (int j = 0; j < 32; j++) {
      const float* r = w0 + j * 6;
      float z = b0[j];
#pragma unroll
      for (int k = 0; k < 6; k++) z += x[k] * r[k];
      s[j] = sp1(z);
    }
#pragma unroll
    for (int j = 0; j < 32; j++) s[j] = hb[j] * sig_h(s[j]);
#pragma unroll
    for (int i = 0; i < 6; i++) {
      const float* r = uw0O + i * 32;  // original layout: row i over j
      float tp = 0.f;
#pragma unroll
      for (int j = 0; j < 32; j++) tp += r[j] * s[j];
      sc[(27 + i) * Bl + e] = tp;
    }
  } else {
    // ================= d: fwd =================
    const float* w0 = W;
    const float* wh = W + 192;
    const float* wo = W + 4288;
    const float* b0 = W + 5440;
    const float* bh = W + 5472;
    const float* bo = W + 5600;
    float xd[6];
#pragma unroll
    for (int i = 0; i < 6; i++) xd[i] = ip[6 + i];
    float h[32], zn[32];
#pragma unroll
    for (int j = 0; j < 32; j++) {
      const float* r = w0 + j * 6;
      float z = b0[j];
#pragma unroll
      for (int k = 0; k < 6; k++) z += x[k] * r[k];
      h[j] = sp1(z);
    }
    fwd_layer(wh + 0 * 1024, bh + 0, h, zn);
    fwd_layer(wh + 1 * 1024, bh + 32, zn, h);
    fwd_layer(wh + 2 * 1024, bh + 64, h, zn);
    fwd_layer(wh + 3 * 1024, bh + 96, zn, h);
    float td[6] = {0, 0, 0, 0, 0, 0};
#pragma unroll
    for (int o = 0; o < 36; o++) {
      const float* r = wo + o * 32;
      float v = bo[o];
#pragma unroll
      for (int k = 0; k < 32; k++) v += h[k] * r[k];
      td[o / 6] += v * xd[o % 6];
    }
#pragma unroll
    for (int i = 0; i < 6; i++) sc[(33 + i) * Bl + e] = td[i];
  }
}

// ---------------- combine + solve ----------------
__global__ __launch_bounds__(256) void combine_kernel(const float* __restrict__ in,
                                                      const float* __restrict__ A,
                                                      const float* __restrict__ sc,
                                                      float* __restrict__ out, int B) {
  int b = blockIdx.x * 256 + threadIdx.x;
  if (b >= B) return;
  const long Bl = B;
  const float* ip = in + (long)b * 18;
  float te[6];
  {
    float tv[6];
#pragma unroll
    for (int i = 0; i < 6; i++) tv[i] = ip[12 + i];
#pragma unroll
    for (int i = 0; i < 6; i++) {
      float s = 0.f;
#pragma unroll
      for (int j = 0; j < 6; j++) s += tv[j] * A[j * 6 + i];
      te[i] = s;
    }
  }
  float Ms[6][6], r[6], y[6];
  {
    int idx = 0;
#pragma unroll
    for (int i = 0; i < 6; i++)
#pragma unroll
      for (int j = i; j < 6; j++) {
        float v = sc[idx * Bl + b];
        Ms[i][j] = v;
        Ms[j][i] = v;
        idx++;
      }
  }
#pragma unroll
  for (int i = 0; i < 6; i++)
    r[i] = te[i] - sc[(21 + i) * Bl + b] - sc[(27 + i) * Bl + b] - sc[(33 + i) * Bl + b];

#pragma unroll
  for (int k = 0; k < 6; k++) {
#pragma unroll
    for (int rr = k + 1; rr < 6; rr++) {
      bool c = fabsf(Ms[rr][k]) > fabsf(Ms[k][k]);
#pragma unroll
      for (int j = 0; j < 6; j++) {
        float a = Ms[k][j], bb = Ms[rr][j];
        Ms[k][j] = c ? bb : a;
        Ms[rr][j] = c ? a : bb;
      }
      float a = r[k], bb = r[rr];
      r[k] = c ? bb : a;
      r[rr] = c ? a : bb;
    }
    float piv = Ms[k][k];
#pragma unroll
    for (int rr = k + 1; rr < 6; rr++) {
      float f = Ms[rr][k] / piv;
#pragma unroll
      for (int j = k; j < 6; j++) Ms[rr][j] -= f * Ms[k][j];
      r[rr] -= f * r[k];
    }
  }
#pragma unroll
  for (int ki = 5; ki >= 0; ki--) {
    float v = r[ki];
#pragma unroll
    for (int j = ki + 1; j < 6; j++) v -= Ms[ki][j] * y[j];
    y[ki] = v / Ms[ki][ki];
  }
  float* op = out + (long)b * 6;
#pragma unroll
  for (int i = 0; i < 6; i++) op[i] = y[i];
}

// ---------------- fallback monolithic kernel (used only if ws too small) ----------------
__global__ __launch_bounds__(64, 1) void lnn_kernel(
    const float* __restrict__ in, const float* __restrict__ A, const float* __restrict__ ws,
    const float* __restrict__ m_b0, const float* __restrict__ m_bh, const float* __restrict__ m_bo,
    const float* __restrict__ u_W0, const float* __restrict__ u_b0, const float* __restrict__ u_Wh,
    const float* __restrict__ u_bh, const float* __restrict__ u_Wo,
    const float* __restrict__ d_b0, const float* __restrict__ d_bh, const float* __restrict__ d_bo,
    float* __restrict__ out, int B) {
  int b = blockIdx.x * 64 + threadIdx.x;
  if (b >= B) return;
  const float* ip = in + (long)b * 18;
  float x[6], xd[6], te[6];
#pragma unroll
  for (int i = 0; i < 6; i++) {
    x[i] = ip[i];
    xd[i] = ip[6 + i];
  }
  {
    float tv[6];
#pragma unroll
    for (int i = 0; i < 6; i++) tv[i] = ip[12 + i];
#pragma unroll
    for (int i = 0; i < 6; i++) {
      float s = 0.f;
#pragma unroll
      for (int j = 0; j < 6; j++) s += tv[j] * A[j * 6 + i];
      te[i] = s;
    }
  }
  float td[6] = {0, 0, 0, 0, 0, 0};
  {
    float h[32], zn[32];
    const float* w0 = ws + DW0T;
#pragma unroll
    for (int j = 0; j < 32; j++) {
      float z = d_b0[j];
#pragma unroll
      for (int k = 0; k < 6; k++) z += x[k] * w0[j * 6 + k];
      h[j] = sp1(z);
    }
    fwd_layer(ws + DWHT + 0 * 1024, d_bh + 0, h, zn);
    fwd_layer(ws + DWHT + 1 * 1024, d_bh + 32, zn, h);
    fwd_layer(ws + DWHT + 2 * 1024, d_bh + 64, h, zn);
    fwd_layer(ws + DWHT + 3 * 1024, d_bh + 96, zn, h);
    const float* wo = ws + DWOT;
#pragma unroll
    for (int o = 0; o < 36; o++) {
      float v = d_bo[o];
#pragma unroll
      for (int k = 0; k < 32; k++) v += h[k] * wo[o * 32 + k];
      td[o / 6] += v * xd[o % 6];
    }
  }
  float tp[6] = {0, 0, 0, 0, 0, 0};
  {
    float hb[32], hd[32], s[32], r2[32];
    const float* w0 = ws + UW0T;
#pragma unroll
    for (int j = 0; j < 32; j++) {
      float z = u_b0[j];
#pragma unroll
      for (int k = 0; k < 6; k++) z += x[k] * w0[j * 6 + k];
      s[j] = sp1(z);
    }
    fwd_layer(ws + UWHT + 0 * 1024, u_bh + 0, s, hb);
    fwd_layer(ws + UWHT + 1 * 1024, u_bh + 32, hb, s);
    fwd_layer(ws + UWHT + 2 * 1024, u_bh + 64, s, hd);
    fwd_layer(ws + UWHT + 3 * 1024, u_bh + 96, hd, s);
#pragma unroll
    for (int j = 0; j < 32; j++) s[j] = u_Wo[j] * sig_h(s[j]);
    bwd_mv(u_Wh + 3 * 1024, s, r2);
#pragma unroll
    for (int j = 0; j < 32; j++) s[j] = r2[j] * sig_h(hd[j]);
    bwd_mv(u_Wh + 2 * 1024, s, hd);
    fwd_layer(ws + UWHT + 1 * 1024, u_bh + 32, hb, s);
#pragma unroll
    for (int j = 0; j < 32; j++) r2[j] = hd[j] * sig_h(s[j]);
    bwd_mv(u_Wh + 1 * 1024, r2, s);
#pragma unroll
    for (int j = 0; j < 32; j++) r2[j] = s[j] * sig_h(hb[j]);
    bwd_mv(u_Wh + 0 * 1024, r2, hb);
#pragma unroll
    for (int j = 0; j < 32; j++) {
      float z = u_b0[j];
#pragma unroll
      for (int k = 0; k < 6; k++) z += x[k] * w0[j * 6 + k];
      s[j] = sp1(z);
    }
#pragma unroll
    for (int j = 0; j < 32; j++) s[j] = hb[j] * sig_h(s[j]);
#pragma unroll
    for (int i = 0; i < 6; i++) {
      float t = 0.f;
#pragma unroll
      for (int j = 0; j < 32; j++) t += u_W0[i * 32 + j] * s[j];
      tp[i] = t;
    }
  }
  float Ms[6][6], tc[6];
  {
    float h[32], t[32], zn[32];
    const float* w0 = ws + MW0T;
#pragma unroll
    for (int j = 0; j < 32; j++) {
      float zh = m_b0[j], zt = 0.f;
#pragma unroll
      for (int k = 0; k < 6; k++) {
        zh += x[k] * w0[j * 6 + k];
        zt += xd[k] * w0[j * 6 + k];
      }
      float hs, sg;
      sp_sig(zh, hs, sg);
      h[j] = hs;
      t[j] = zt * sg;
    }
    m_layer(ws + MWHT + 0 * 1024, m_bh + 0, h, t, zn);
    m_layer(ws + MWHT + 1 * 1024, m_bh + 32, h, zn, t);
    m_layer(ws + MWHT + 2 * 1024, m_bh + 64, h, t, zn);
    m_layer(ws + MWHT + 3 * 1024, m_bh + 96, h, zn, t);
    const float* wo = ws + MWOT;
    float Msv[21];
    int idx = 0;
#pragma unroll
    for (int i = 0; i < 6; i++) tc[i] = 0.f;
#pragma unroll
    for (int i = 0; i < 6; i++)
#pragma unroll
      for (int j = i; j < 6; j++) {
        const float* r = wo + (i * 6 + j) * 32;
        float v = m_bo[i * 6 + j], w = 0.f;
#pragma unroll
        for (int k = 0; k < 32; k++) {
          v += h[k] * r[k];
          w += t[k] * r[k];
        }
        if (i != j) {
          const float* rr = wo + (j * 6 + i) * 32;
          float v2 = m_bo[j * 6 + i], w2 = 0.f;
#pragma unroll
          for (int k = 0; k < 32; k++) {
            v2 += h[k] * rr[k];
            w2 += t[k] * rr[k];
          }
          v = 0.5f * (v + v2);
          w = 0.5f * (w + w2);
        }
        Msv[idx] = v;
        tc[i] += w * xd[j];
        if (j != i) tc[j] += w * xd[i];
        idx++;
      }
    idx = 0;
#pragma unroll
    for (int i = 0; i < 6; i++)
#pragma unroll
      for (int j = i; j < 6; j++) {
        Ms[i][j] = Msv[idx];
        Ms[j][i] = Msv[idx];
        idx++;
      }
  }
  float r[6], y[6];
#pragma unroll
  for (int i = 0; i < 6; i++) r[i] = te[i] - tc[i] - tp[i] - td[i];
#pragma unroll
  for (int k = 0; k < 6; k++) {
#pragma unroll
    for (int rr = k + 1; rr < 6; rr++) {
      bool c = fabsf(Ms[rr][k]) > fabsf(Ms[k][k]);
#pragma unroll
      for (int j = 0; j < 6; j++) {
        float a = Ms[k][j], bb = Ms[rr][j];
        Ms[k][j] = c ? bb : a;
        Ms[rr][j] = c ? a : bb;
      }
      float a = r[k], bb = r[rr];
      r[k] = c ? bb : a;
      r[rr] = c ? a : bb;
    }
    float piv = Ms[k][k];
#pragma unroll
    for (int rr = k + 1; rr < 6; rr++) {
      float f = Ms[rr][k] / piv;
#pragma unroll
      for (int j = k; j < 6; j++) Ms[rr][j] -= f * Ms[k][j];
      r[rr] -= f * r[k];
    }
  }
#pragma unroll
  for (int ki = 5; ki >= 0; ki--) {
    float v = r[ki];
#pragma unroll
    for (int j = ki + 1; j < 6; j++) v -= Ms[ki][j] * y[j];
    y[ki] = v / Ms[ki][ki];
  }
  float* op = out + (long)b * 6;
#pragma unroll
  for (int i = 0; i < 6; i++) op[i] = y[i];
}

extern "C" void kernel_launch(void* const* d_in, const int* in_sizes, int n_in, void* d_out,
                              int out_size, void* d_ws, size_t ws_size, hipStream_t stream) {
  const float* inputs = (const float*)d_in[0];
  const float* A = (const float*)d_in[1];
  const float* m_W0 = (const float*)d_in[2];
  const float* m_b0 = (const float*)d_in[3];
  const float* m_Wh = (const float*)d_in[4];
  const float* m_bh = (const float*)d_in[5];
  const float* m_Wo = (const float*)d_in[6];
  const float* m_bo = (const float*)d_in[7];
  const float* u_W0 = (const float*)d_in[8];
  const float* u_b0 = (const float*)d_in[9];
  const float* u_Wh = (const float*)d_in[10];
  const float* u_bh = (const float*)d_in[11];
  const float* u_Wo = (const float*)d_in[12];
  const float* d_W0 = (const float*)d_in[14];
  const float* d_b0 = (const float*)d_in[15];
  const float* d_Wh = (const float*)d_in[16];
  const float* d_bh = (const float*)d_in[17];
  const float* d_Wo = (const float*)d_in[18];
  const float* d_bo = (const float*)d_in[19];

  float* ws = (float*)d_ws;
  float* out = (float*)d_out;
  int B = in_sizes[0] / 18;

  prep_kernel<<<16, 256, 0, stream>>>(m_W0, m_Wh, m_Wo, u_W0, u_Wh, u_Wo, d_W0, d_Wh, d_Wo, ws);

  size_t need = (size_t)(SC_BASE + (size_t)B * 39) * 4;
  if (ws_size >= need) {
    float* sc = ws + SC_BASE;
    int nb = (B + 255) / 256;
    roles3_lds_kernel<<<3 * nb, 256, 0, stream>>>(inputs, ws, m_b0, m_bh, m_bo, u_W0, u_b0, u_Wh,
                                                  u_bh, u_Wo, d_b0, d_bh, d_bo, sc, B);
    combine_kernel<<<(B + 255) / 256, 256, 0, stream>>>(inputs, A, sc, out, B);
  } else {
    lnn_kernel<<<(B + 63) / 64, 64, 0, stream>>>(inputs, A, ws, m_b0, m_bh, m_bo, u_W0, u_b0, u_Wh,
                                                 u_bh, u_Wo, d_b0, d_bh, d_bo, out, B);
  }
}

// Round 4
// 160.018 us; speedup vs baseline: 1.7761x; 1.7761x over previous
//
#include <hip/hip_runtime.h>

// LnnDynamics, role-per-block + LDS-weight version (v5):
//   role 0 (m): M-MLP fwd + JVP along qd -> Ms[21] (symmetrized), tc[6]
//   role 1 (u): U-MLP fwd + checkpointed reverse-mode -> tau_pot[6]
//   role 2 (d): D-MLP fwd -> tau_d[6]
//   combine:   r = tau@A - tc - tp - td ; solve Msym y = r
// v4 -> v5: launch_bounds (256,2) -> (256,1); LDS padding removed.
// Empirical allocator rule from v1-v4: VGPR budget = 512/(2*arg)
//   (64,1)->132 ok | (256,3)->84 spill | (256,2)->128 spill | pad: no effect
// arg=1 -> 256-VGPR budget -> the ~190-reg peak (u-role 4x32 arrays +
// in-flight ds_reads) fits with no spill. VGPR>128 then naturally caps
// residency at 2 waves/SIMD (2 blocks/CU, 70KB LDS of 160).
// Scratch sc is SoA: sc[field*B + b], fields 0-20 Ms, 21-26 tc, 27-32 tp, 33-38 td.

#define NQ 6
#define HID 32
#define NHID 4  // NL-1

// workspace float offsets (transposed weights, built by prep_kernel)
#define MW0T 0
#define UW0T 192
#define DW0T 384
#define MWHT 576
#define UWHT (576 + 4096)
#define DWHT (576 + 8192)
#define MWOT (576 + 12288)
#define DWOT (MWOT + 1152)
#define UWOT (DWOT + 1152)
#define SC_BASE 16384  // per-element scratch starts here (floats)

// LDS layout (floats):
//  role m/d: [0:192) W0t | [192:4288) Wht | [4288:5440) Wot
//            [5440:5472) b0 | [5472:5600) bh | [5600:5636) bo
//  role u:   [0:192) W0t | [192:4288) Wht | [4288:8384) Wh-original
//            [8384:8416) Wo | [8416:8608) W0-original
//            [8608:8640) b0 | [8640:8768) bh
#define LDS_FLOATS 8768

__global__ void prep_kernel(const float* __restrict__ mW0, const float* __restrict__ mWh,
                            const float* __restrict__ mWo, const float* __restrict__ uW0,
                            const float* __restrict__ uWh, const float* __restrict__ uWo,
                            const float* __restrict__ dW0, const float* __restrict__ dWh,
                            const float* __restrict__ dWo, float* __restrict__ ws) {
  int t = blockIdx.x * blockDim.x + threadIdx.x;
  if (t < 192) {  // W0t[j*6+k] = W0[k*32+j]
    int j = t / 6, k = t % 6;
    ws[MW0T + t] = mW0[k * HID + j];
    ws[UW0T + t] = uW0[k * HID + j];
    ws[DW0T + t] = dW0[k * HID + j];
  }
  if (t < 4096) {  // Wht[(l*32+j)*32+k] = Wh[(l*32+k)*32+j]
    int l = t >> 10, j = (t >> 5) & 31, k = t & 31;
    int src = l * 1024 + k * 32 + j;
    ws[MWHT + t] = mWh[src];
    ws[UWHT + t] = uWh[src];
    ws[DWHT + t] = dWh[src];
  }
  if (t < 1152) {  // Wot[o*32+k] = Wo[k*36+o]
    int o = t / 32, k = t % 32;
    ws[MWOT + t] = mWo[k * 36 + o];
    ws[DWOT + t] = dWo[k * 36 + o];
  }
  if (t < 32) ws[UWOT + t] = uWo[t];
}

__device__ __forceinline__ float sp1(float z) {
  return fmaxf(z, 0.f) + __logf(1.f + __expf(-fabsf(z)));
}
__device__ __forceinline__ void sp_sig(float z, float& hs, float& sg) {
  float e = __expf(-fabsf(z));
  float d = __builtin_amdgcn_rcpf(1.f + e);
  hs = fmaxf(z, 0.f) + __logf(1.f + e);
  sg = (z >= 0.f ? 1.f : e) * d;
}
// h = softplus(z) >= 0  =>  sigmoid(z) = 1 - exp(-h)
__device__ __forceinline__ float sig_h(float h) { return 1.f - __expf(-h); }

// block-cooperative copies into LDS (256 threads)
__device__ __forceinline__ void cpy4(float* __restrict__ dst, const float* __restrict__ src,
                                     int n4, int t) {
  const float4* s = (const float4*)src;
  float4* d = (float4*)dst;
  for (int i = t; i < n4; i += 256) d[i] = s[i];
}
__device__ __forceinline__ void cpys(float* __restrict__ dst, const float* __restrict__ src, int n,
                                     int t) {
  for (int i = t; i < n; i += 256) dst[i] = src[i];
}

// m-role layer, two-pass (keeps only h + tin + tout live):
//   pass A: tout_j = zh_j = h . Wt_j + b_j
//   pass B: zt_j = tin . Wt_j ; h_j = softplus(zh_j) ; tout_j = zt_j * sigmoid(zh_j)
__device__ __forceinline__ void m_layer(const float* __restrict__ Wb, const float* __restrict__ bh,
                                        float* __restrict__ h, const float* __restrict__ tin,
                                        float* __restrict__ tout) {
#pragma unroll
  for (int j = 0; j < 32; j++) {
    const float* r = Wb + j * 32;
    float z = bh[j];
#pragma unroll
    for (int k = 0; k < 32; k++) z += h[k] * r[k];
    tout[j] = z;
  }
#pragma unroll
  for (int j = 0; j < 32; j++) {
    const float* r = Wb + j * 32;
    float z = 0.f;
#pragma unroll
    for (int k = 0; k < 32; k++) z += tin[k] * r[k];
    float hs, sg;
    sp_sig(tout[j], hs, sg);
    h[j] = hs;
    tout[j] = z * sg;
  }
}

// plain forward layer: hout = softplus(hin @ Wt + b)
__device__ __forceinline__ void fwd_layer(const float* __restrict__ Wb,
                                          const float* __restrict__ bh,
                                          const float* __restrict__ hin, float* __restrict__ hout) {
#pragma unroll
  for (int j = 0; j < 32; j++) {
    const float* r = Wb + j * 32;
    float z = bh[j];
#pragma unroll
    for (int k = 0; k < 32; k++) z += hin[k] * r[k];
    hout[j] = sp1(z);
  }
}

// backward matvec vs ORIGINAL-layout Wh rows: gout[k] = sum_j Wh[k][j] * gin[j]
__device__ __forceinline__ void bwd_mv(const float* __restrict__ Worig,
                                       const float* __restrict__ gin, float* __restrict__ gout) {
#pragma unroll
  for (int k = 0; k < 32; k++) {
    const float* r = Worig + k * 32;
    float s = 0.f;
#pragma unroll
    for (int j = 0; j < 32; j++) s += r[j] * gin[j];
    gout[k] = s;
  }
}

__global__ __launch_bounds__(256, 1) void roles3_lds_kernel(
    const float* __restrict__ in, const float* __restrict__ ws, const float* __restrict__ m_b0,
    const float* __restrict__ m_bh, const float* __restrict__ m_bo, const float* __restrict__ u_W0,
    const float* __restrict__ u_b0, const float* __restrict__ u_Wh, const float* __restrict__ u_bh,
    const float* __restrict__ u_Wo, const float* __restrict__ d_b0, const float* __restrict__ d_bh,
    const float* __restrict__ d_bo, float* __restrict__ sc, int B) {
  __shared__ __align__(16) float W[LDS_FLOATS];
  const int role = blockIdx.x % 3;
  const int t = threadIdx.x;

  // ---- stage role weights + biases into LDS ----
  if (role == 0) {
    cpy4(W, ws + MW0T, 48, t);
    cpy4(W + 192, ws + MWHT, 1024, t);
    cpy4(W + 4288, ws + MWOT, 288, t);
    cpys(W + 5440, m_b0, 32, t);
    cpys(W + 5472, m_bh, 128, t);
    cpys(W + 5600, m_bo, 36, t);
  } else if (role == 1) {
    cpy4(W, ws + UW0T, 48, t);
    cpy4(W + 192, ws + UWHT, 1024, t);
    cpy4(W + 4288, u_Wh, 1024, t);  // original layout for bwd
    cpy4(W + 8384, u_Wo, 8, t);
    cpy4(W + 8416, u_W0, 48, t);  // original layout for final grad
    cpys(W + 8608, u_b0, 32, t);
    cpys(W + 8640, u_bh, 128, t);
  } else {
    cpy4(W, ws + DW0T, 48, t);
    cpy4(W + 192, ws + DWHT, 1024, t);
    cpy4(W + 4288, ws + DWOT, 288, t);
    cpys(W + 5440, d_b0, 32, t);
    cpys(W + 5472, d_bh, 128, t);
    cpys(W + 5600, d_bo, 36, t);
  }
  __syncthreads();

  const int e = (blockIdx.x / 3) * 256 + t;
  if (e >= B) return;
  const float* ip = in + (long)e * 18;
  const long Bl = B;

  float x[6];
#pragma unroll
  for (int i = 0; i < 6; i++) x[i] = ip[i];

  if (role == 0) {
    // ================= m: fwd + JVP =================
    const float* w0 = W;
    const float* wh = W + 192;
    const float* wo = W + 4288;
    const float* b0 = W + 5440;
    const float* bh = W + 5472;
    const float* bo = W + 5600;
    float xd[6];
#pragma unroll
    for (int i = 0; i < 6; i++) xd[i] = ip[6 + i];
    float h[32], tv[32], zn[32];
#pragma unroll
    for (int j = 0; j < 32; j++) {
      const float* r = w0 + j * 6;
      float zh = b0[j], zt = 0.f;
#pragma unroll
      for (int k = 0; k < 6; k++) {
        zh += x[k] * r[k];
        zt += xd[k] * r[k];
      }
      float hs, sg;
      sp_sig(zh, hs, sg);
      h[j] = hs;
      tv[j] = zt * sg;
    }
    m_layer(wh + 0 * 1024, bh + 0, h, tv, zn);
    m_layer(wh + 1 * 1024, bh + 32, h, zn, tv);
    m_layer(wh + 2 * 1024, bh + 64, h, tv, zn);
    m_layer(wh + 3 * 1024, bh + 96, h, zn, tv);
    // symmetrized output, pairwise
    float Ms[21], tc[6] = {0, 0, 0, 0, 0, 0};
    int idx = 0;
#pragma unroll
    for (int i = 0; i < 6; i++)
#pragma unroll
      for (int j = i; j < 6; j++) {
        const float* r = wo + (i * 6 + j) * 32;
        float v = bo[i * 6 + j], w = 0.f;
#pragma unroll
        for (int k = 0; k < 32; k++) {
          v += h[k] * r[k];
          w += tv[k] * r[k];
        }
        if (i != j) {
          const float* r2 = wo + (j * 6 + i) * 32;
          float v2 = bo[j * 6 + i], w2 = 0.f;
#pragma unroll
          for (int k = 0; k < 32; k++) {
            v2 += h[k] * r2[k];
            w2 += tv[k] * r2[k];
          }
          v = 0.5f * (v + v2);
          w = 0.5f * (w + w2);
        }
        Ms[idx] = v;
        tc[i] += w * xd[j];
        if (j != i) tc[j] += w * xd[i];
        idx++;
      }
#pragma unroll
    for (int f = 0; f < 21; f++) sc[f * Bl + e] = Ms[f];
#pragma unroll
    for (int i = 0; i < 6; i++) sc[(21 + i) * Bl + e] = tc[i];
  } else if (role == 1) {
    // ================= u: fwd + checkpointed bwd =================
    const float* w0 = W;
    const float* wh = W + 192;    // transposed (fwd)
    const float* whO = W + 4288;  // original (bwd)
    const float* uwo = W + 8384;
    const float* uw0O = W + 8416;
    const float* b0 = W + 8608;
    const float* bh = W + 8640;
    float hb[32], hd[32], s[32], r2[32];
    // ha -> s
#pragma unroll
    for (int j = 0; j < 32; j++) {
      const float* r = w0 + j * 6;
      float z = b0[j];
#pragma unroll
      for (int k = 0; k < 6; k++) z += x[k] * r[k];
      s[j] = sp1(z);
    }
    fwd_layer(wh + 0 * 1024, bh + 0, s, hb);   // hb (checkpoint)
    fwd_layer(wh + 1 * 1024, bh + 32, hb, s);  // hc (dropped, recomputed later)
    fwd_layer(wh + 2 * 1024, bh + 64, s, hd);  // hd (checkpoint)
    fwd_layer(wh + 3 * 1024, bh + 96, hd, s);  // he
    // g = Wo * sig(he), in place in s
#pragma unroll
    for (int j = 0; j < 32; j++) s[j] = uwo[j] * sig_h(s[j]);
    bwd_mv(whO + 3 * 1024, s, r2);
#pragma unroll
    for (int j = 0; j < 32; j++) s[j] = r2[j] * sig_h(hd[j]);  // hd dead
    bwd_mv(whO + 2 * 1024, s, hd);                             // gn -> hd
    fwd_layer(wh + 1 * 1024, bh + 32, hb, s);                  // recompute hc -> s
#pragma unroll
    for (int j = 0; j < 32; j++) r2[j] = hd[j] * sig_h(s[j]);
    bwd_mv(whO + 1 * 1024, r2, s);
#pragma unroll
    for (int j = 0; j < 32; j++) r2[j] = s[j] * sig_h(hb[j]);  // hb dead
    bwd_mv(whO + 0 * 1024, r2, hb);
    // recompute ha -> s
#pragma unroll
    for (int j = 0; j < 32; j++) {
      const float* r = w0 + j * 6;
      float z = b0[j];
#pragma unroll
      for (int k = 0; k < 6; k++) z += x[k] * r[k];
      s[j] = sp1(z);
    }
#pragma unroll
    for (int j = 0; j < 32; j++) s[j] = hb[j] * sig_h(s[j]);
#pragma unroll
    for (int i = 0; i < 6; i++) {
      const float* r = uw0O + i * 32;  // original layout: row i over j
      float tp = 0.f;
#pragma unroll
      for (int j = 0; j < 32; j++) tp += r[j] * s[j];
      sc[(27 + i) * Bl + e] = tp;
    }
  } else {
    // ================= d: fwd =================
    const float* w0 = W;
    const float* wh = W + 192;
    const float* wo = W + 4288;
    const float* b0 = W + 5440;
    const float* bh = W + 5472;
    const float* bo = W + 5600;
    float xd[6];
#pragma unroll
    for (int i = 0; i < 6; i++) xd[i] = ip[6 + i];
    float h[32], zn[32];
#pragma unroll
    for (int j = 0; j < 32; j++) {
      const float* r = w0 + j * 6;
      float z = b0[j];
#pragma unroll
      for (int k = 0; k < 6; k++) z += x[k] * r[k];
      h[j] = sp1(z);
    }
    fwd_layer(wh + 0 * 1024, bh + 0, h, zn);
    fwd_layer(wh + 1 * 1024, bh + 32, zn, h);
    fwd_layer(wh + 2 * 1024, bh + 64, h, zn);
    fwd_layer(wh + 3 * 1024, bh + 96, zn, h);
    float td[6] = {0, 0, 0, 0, 0, 0};
#pragma unroll
    for (int o = 0; o < 36; o++) {
      const float* r = wo + o * 32;
      float v = bo[o];
#pragma unroll
      for (int k = 0; k < 32; k++) v += h[k] * r[k];
      td[o / 6] += v * xd[o % 6];
    }
#pragma unroll
    for (int i = 0; i < 6; i++) sc[(33 + i) * Bl + e] = td[i];
  }
}

// ---------------- combine + solve ----------------
__global__ __launch_bounds__(256) void combine_kernel(const float* __restrict__ in,
                                                      const float* __restrict__ A,
                                                      const float* __restrict__ sc,
                                                      float* __restrict__ out, int B) {
  int b = blockIdx.x * 256 + threadIdx.x;
  if (b >= B) return;
  const long Bl = B;
  const float* ip = in + (long)b * 18;
  float te[6];
  {
    float tv[6];
#pragma unroll
    for (int i = 0; i < 6; i++) tv[i] = ip[12 + i];
#pragma unroll
    for (int i = 0; i < 6; i++) {
      float s = 0.f;
#pragma unroll
      for (int j = 0; j < 6; j++) s += tv[j] * A[j * 6 + i];
      te[i] = s;
    }
  }
  float Ms[6][6], r[6], y[6];
  {
    int idx = 0;
#pragma unroll
    for (int i = 0; i < 6; i++)
#pragma unroll
      for (int j = i; j < 6; j++) {
        float v = sc[idx * Bl + b];
        Ms[i][j] = v;
        Ms[j][i] = v;
        idx++;
      }
  }
#pragma unroll
  for (int i = 0; i < 6; i++)
    r[i] = te[i] - sc[(21 + i) * Bl + b] - sc[(27 + i) * Bl + b] - sc[(33 + i) * Bl + b];

#pragma unroll
  for (int k = 0; k < 6; k++) {
#pragma unroll
    for (int rr = k + 1; rr < 6; rr++) {
      bool c = fabsf(Ms[rr][k]) > fabsf(Ms[k][k]);
#pragma unroll
      for (int j = 0; j < 6; j++) {
        float a = Ms[k][j], bb = Ms[rr][j];
        Ms[k][j] = c ? bb : a;
        Ms[rr][j] = c ? a : bb;
      }
      float a = r[k], bb = r[rr];
      r[k] = c ? bb : a;
      r[rr] = c ? a : bb;
    }
    float piv = Ms[k][k];
#pragma unroll
    for (int rr = k + 1; rr < 6; rr++) {
      float f = Ms[rr][k] / piv;
#pragma unroll
      for (int j = k; j < 6; j++) Ms[rr][j] -= f * Ms[k][j];
      r[rr] -= f * r[k];
    }
  }
#pragma unroll
  for (int ki = 5; ki >= 0; ki--) {
    float v = r[ki];
#pragma unroll
    for (int j = ki + 1; j < 6; j++) v -= Ms[ki][j] * y[j];
    y[ki] = v / Ms[ki][ki];
  }
  float* op = out + (long)b * 6;
#pragma unroll
  for (int i = 0; i < 6; i++) op[i] = y[i];
}

// ---------------- fallback monolithic kernel (used only if ws too small) ----------------
__global__ __launch_bounds__(64, 1) void lnn_kernel(
    const float* __restrict__ in, const float* __restrict__ A, const float* __restrict__ ws,
    const float* __restrict__ m_b0, const float* __restrict__ m_bh, const float* __restrict__ m_bo,
    const float* __restrict__ u_W0, const float* __restrict__ u_b0, const float* __restrict__ u_Wh,
    const float* __restrict__ u_bh, const float* __restrict__ u_Wo,
    const float* __restrict__ d_b0, const float* __restrict__ d_bh, const float* __restrict__ d_bo,
    float* __restrict__ out, int B) {
  int b = blockIdx.x * 64 + threadIdx.x;
  if (b >= B) return;
  const float* ip = in + (long)b * 18;
  float x[6], xd[6], te[6];
#pragma unroll
  for (int i = 0; i < 6; i++) {
    x[i] = ip[i];
    xd[i] = ip[6 + i];
  }
  {
    float tv[6];
#pragma unroll
    for (int i = 0; i < 6; i++) tv[i] = ip[12 + i];
#pragma unroll
    for (int i = 0; i < 6; i++) {
      float s = 0.f;
#pragma unroll
      for (int j = 0; j < 6; j++) s += tv[j] * A[j * 6 + i];
      te[i] = s;
    }
  }
  float td[6] = {0, 0, 0, 0, 0, 0};
  {
    float h[32], zn[32];
    const float* w0 = ws + DW0T;
#pragma unroll
    for (int j = 0; j < 32; j++) {
      float z = d_b0[j];
#pragma unroll
      for (int k = 0; k < 6; k++) z += x[k] * w0[j * 6 + k];
      h[j] = sp1(z);
    }
    fwd_layer(ws + DWHT + 0 * 1024, d_bh + 0, h, zn);
    fwd_layer(ws + DWHT + 1 * 1024, d_bh + 32, zn, h);
    fwd_layer(ws + DWHT + 2 * 1024, d_bh + 64, h, zn);
    fwd_layer(ws + DWHT + 3 * 1024, d_bh + 96, zn, h);
    const float* wo = ws + DWOT;
#pragma unroll
    for (int o = 0; o < 36; o++) {
      float v = d_bo[o];
#pragma unroll
      for (int k = 0; k < 32; k++) v += h[k] * wo[o * 32 + k];
      td[o / 6] += v * xd[o % 6];
    }
  }
  float tp[6] = {0, 0, 0, 0, 0, 0};
  {
    float hb[32], hd[32], s[32], r2[32];
    const float* w0 = ws + UW0T;
#pragma unroll
    for (int j = 0; j < 32; j++) {
      float z = u_b0[j];
#pragma unroll
      for (int k = 0; k < 6; k++) z += x[k] * w0[j * 6 + k];
      s[j] = sp1(z);
    }
    fwd_layer(ws + UWHT + 0 * 1024, u_bh + 0, s, hb);
    fwd_layer(ws + UWHT + 1 * 1024, u_bh + 32, hb, s);
    fwd_layer(ws + UWHT + 2 * 1024, u_bh + 64, s, hd);
    fwd_layer(ws + UWHT + 3 * 1024, u_bh + 96, hd, s);
#pragma unroll
    for (int j = 0; j < 32; j++) s[j] = u_Wo[j] * sig_h(s[j]);
    bwd_mv(u_Wh + 3 * 1024, s, r2);
#pragma unroll
    for (int j = 0; j < 32; j++) s[j] = r2[j] * sig_h(hd[j]);
    bwd_mv(u_Wh + 2 * 1024, s, hd);
    fwd_layer(ws + UWHT + 1 * 1024, u_bh + 32, hb, s);
#pragma unroll
    for (int j = 0; j < 32; j++) r2[j] = hd[j] * sig_h(s[j]);
    bwd_mv(u_Wh + 1 * 1024, r2, s);
#pragma unroll
    for (int j = 0; j < 32; j++) r2[j] = s[j] * sig_h(hb[j]);
    bwd_mv(u_Wh + 0 * 1024, r2, hb);
#pragma unroll
    for (int j = 0; j < 32; j++) {
      float z = u_b0[j];
#pragma unroll
      for (int k = 0; k < 6; k++) z += x[k] * w0[j * 6 + k];
      s[j] = sp1(z);
    }
#pragma unroll
    for (int j = 0; j < 32; j++) s[j] = hb[j] * sig_h(s[j]);
#pragma unroll
    for (int i = 0; i < 6; i++) {
      float t = 0.f;
#pragma unroll
      for (int j = 0; j < 32; j++) t += u_W0[i * 32 + j] * s[j];
      tp[i] = t;
    }
  }
  float Ms[6][6], tc[6];
  {
    float h[32], t[32], zn[32];
    const float* w0 = ws + MW0T;
#pragma unroll
    for (int j = 0; j < 32; j++) {
      float zh = m_b0[j], zt = 0.f;
#pragma unroll
      for (int k = 0; k < 6; k++) {
        zh += x[k] * w0[j * 6 + k];
        zt += xd[k] * w0[j * 6 + k];
      }
      float hs, sg;
      sp_sig(zh, hs, sg);
      h[j] = hs;
      t[j] = zt * sg;
    }
    m_layer(ws + MWHT + 0 * 1024, m_bh + 0, h, t, zn);
    m_layer(ws + MWHT + 1 * 1024, m_bh + 32, h, zn, t);
    m_layer(ws + MWHT + 2 * 1024, m_bh + 64, h, t, zn);
    m_layer(ws + MWHT + 3 * 1024, m_bh + 96, h, zn, t);
    const float* wo = ws + MWOT;
    float Msv[21];
    int idx = 0;
#pragma unroll
    for (int i = 0; i < 6; i++) tc[i] = 0.f;
#pragma unroll
    for (int i = 0; i < 6; i++)
#pragma unroll
      for (int j = i; j < 6; j++) {
        const float* r = wo + (i * 6 + j) * 32;
        float v = m_bo[i * 6 + j], w = 0.f;
#pragma unroll
        for (int k = 0; k < 32; k++) {
          v += h[k] * r[k];
          w += t[k] * r[k];
        }
        if (i != j) {
          const float* rr = wo + (j * 6 + i) * 32;
          float v2 = m_bo[j * 6 + i], w2 = 0.f;
#pragma unroll
          for (int k = 0; k < 32; k++) {
            v2 += h[k] * rr[k];
            w2 += t[k] * rr[k];
          }
          v = 0.5f * (v + v2);
          w = 0.5f * (w + w2);
        }
        Msv[idx] = v;
        tc[i] += w * xd[j];
        if (j != i) tc[j] += w * xd[i];
        idx++;
      }
    idx = 0;
#pragma unroll
    for (int i = 0; i < 6; i++)
#pragma unroll
      for (int j = i; j < 6; j++) {
        Ms[i][j] = Msv[idx];
        Ms[j][i] = Msv[idx];
        idx++;
      }
  }
  float r[6], y[6];
#pragma unroll
  for (int i = 0; i < 6; i++) r[i] = te[i] - tc[i] - tp[i] - td[i];
#pragma unroll
  for (int k = 0; k < 6; k++) {
#pragma unroll
    for (int rr = k + 1; rr < 6; rr++) {
      bool c = fabsf(Ms[rr][k]) > fabsf(Ms[k][k]);
#pragma unroll
      for (int j = 0; j < 6; j++) {
        float a = Ms[k][j], bb = Ms[rr][j];
        Ms[k][j] = c ? bb : a;
        Ms[rr][j] = c ? a : bb;
      }
      float a = r[k], bb = r[rr];
      r[k] = c ? bb : a;
      r[rr] = c ? a : bb;
    }
    float piv = Ms[k][k];
#pragma unroll
    for (int rr = k + 1; rr < 6; rr++) {
      float f = Ms[rr][k] / piv;
#pragma unroll
      for (int j = k; j < 6; j++) Ms[rr][j] -= f * Ms[k][j];
      r[rr] -= f * r[k];
    }
  }
#pragma unroll
  for (int ki = 5; ki >= 0; ki--) {
    float v = r[ki];
#pragma unroll
    for (int j = ki + 1; j < 6; j++) v -= Ms[ki][j] * y[j];
    y[ki] = v / Ms[ki][ki];
  }
  float* op = out + (long)b * 6;
#pragma unroll
  for (int i = 0; i < 6; i++) op[i] = y[i];
}

extern "C" void kernel_launch(void* const* d_in, const int* in_sizes, int n_in, void* d_out,
                              int out_size, void* d_ws, size_t ws_size, hipStream_t stream) {
  const float* inputs = (const float*)d_in[0];
  const float* A = (const float*)d_in[1];
  const float* m_W0 = (const float*)d_in[2];
  const float* m_b0 = (const float*)d_in[3];
  const float* m_Wh = (const float*)d_in[4];
  const float* m_bh = (const float*)d_in[5];
  const float* m_Wo = (const float*)d_in[6];
  const float* m_bo = (const float*)d_in[7];
  const float* u_W0 = (const float*)d_in[8];
  const float* u_b0 = (const float*)d_in[9];
  const float* u_Wh = (const float*)d_in[10];
  const float* u_bh = (const float*)d_in[11];
  const float* u_Wo = (const float*)d_in[12];
  const float* d_W0 = (const float*)d_in[14];
  const float* d_b0 = (const float*)d_in[15];
  const float* d_Wh = (const float*)d_in[16];
  const float* d_bh = (const float*)d_in[17];
  const float* d_Wo = (const float*)d_in[18];
  const float* d_bo = (const float*)d_in[19];

  float* ws = (float*)d_ws;
  float* out = (float*)d_out;
  int B = in_sizes[0] / 18;

  prep_kernel<<<16, 256, 0, stream>>>(m_W0, m_Wh, m_Wo, u_W0, u_Wh, u_Wo, d_W0, d_Wh, d_Wo, ws);

  size_t need = (size_t)(SC_BASE + (size_t)B * 39) * 4;
  if (ws_size >= need) {
    float* sc = ws + SC_BASE;
    int nb = (B + 255) / 256;
    roles3_lds_kernel<<<3 * nb, 256, 0, stream>>>(inputs, ws, m_b0, m_bh, m_bo, u_W0, u_b0, u_Wh,
                                                  u_bh, u_Wo, d_b0, d_bh, d_bo, sc, B);
    combine_kernel<<<(B + 255) / 256, 256, 0, stream>>>(inputs, A, sc, out, B);
  } else {
    lnn_kernel<<<(B + 63) / 64, 64, 0, stream>>>(inputs, A, ws, m_b0, m_bh, m_bo, u_W0, u_b0, u_Wh,
                                                 u_bh, u_Wo, d_b0, d_bh, d_bo, out, B);
  }
}

// Round 5
// 157.569 us; speedup vs baseline: 1.8037x; 1.0155x over previous
//
#include <hip/hip_runtime.h>

// LnnDynamics v6: role-per-block, LDS weights, launch_bounds(256,1).
// v5 analysis: LDS pipe is binding (VALUBusy 40%): per element-layer the
// wave issues 4 broadcast ds_read_b128 (c~4-5cyc, 1 pipe/CU) vs 16 FMA
// (2cyc, 4 SIMDs/CU) -> LDS:VALU ~ 2.4:1. v6 cuts LDS instructions:
//  (1) m_layer fused single-pass: read each weight row once, compute
//      both zh (value) and zt (JVP) dots -> m hidden LDS halved.
//  (2) u-role bwd matvecs read global u_Wh via wave-uniform s_load
//      streams (scalar pipe + K$, 16KB working set) -> 1024 wave-reads
//      moved off the LDS pipe.
// Keep __launch_bounds__(256,1): empirical allocator rule is
// budget = 512/(2*arg); arg=1 -> 256 budget -> no spill at ~200-240 VGPR
// (v2-v5 A/B evidence; v5: VGPR=200, WRITE_SIZE 10MB, 160us).
// Scratch sc is SoA: sc[field*B + b], fields 0-20 Ms, 21-26 tc, 27-32 tp, 33-38 td.

#define NQ 6
#define HID 32
#define NHID 4  // NL-1

// workspace float offsets (transposed weights, built by prep_kernel)
#define MW0T 0
#define UW0T 192
#define DW0T 384
#define MWHT 576
#define UWHT (576 + 4096)
#define DWHT (576 + 8192)
#define MWOT (576 + 12288)
#define DWOT (MWOT + 1152)
#define UWOT (DWOT + 1152)
#define SC_BASE 16384  // per-element scratch starts here (floats)

// LDS layout (floats):
//  role m/d: [0:192) W0t | [192:4288) Wht | [4288:5440) Wot
//            [5440:5472) b0 | [5472:5600) bh | [5600:5636) bo
//  role u:   [0:192) W0t | [192:4288) Wht | [4288:4320) Wo
//            [4320:4512) W0-original | [4512:4544) b0 | [4544:4672) bh
//            (bwd Wh stays in GLOBAL memory -> scalar s_load path)
#define LDS_FLOATS 8768

__global__ void prep_kernel(const float* __restrict__ mW0, const float* __restrict__ mWh,
                            const float* __restrict__ mWo, const float* __restrict__ uW0,
                            const float* __restrict__ uWh, const float* __restrict__ uWo,
                            const float* __restrict__ dW0, const float* __restrict__ dWh,
                            const float* __restrict__ dWo, float* __restrict__ ws) {
  int t = blockIdx.x * blockDim.x + threadIdx.x;
  if (t < 192) {  // W0t[j*6+k] = W0[k*32+j]
    int j = t / 6, k = t % 6;
    ws[MW0T + t] = mW0[k * HID + j];
    ws[UW0T + t] = uW0[k * HID + j];
    ws[DW0T + t] = dW0[k * HID + j];
  }
  if (t < 4096) {  // Wht[(l*32+j)*32+k] = Wh[(l*32+k)*32+j]
    int l = t >> 10, j = (t >> 5) & 31, k = t & 31;
    int src = l * 1024 + k * 32 + j;
    ws[MWHT + t] = mWh[src];
    ws[UWHT + t] = uWh[src];
    ws[DWHT + t] = dWh[src];
  }
  if (t < 1152) {  // Wot[o*32+k] = Wo[k*36+o]
    int o = t / 32, k = t % 32;
    ws[MWOT + t] = mWo[k * 36 + o];
    ws[DWOT + t] = dWo[k * 36 + o];
  }
  if (t < 32) ws[UWOT + t] = uWo[t];
}

__device__ __forceinline__ float sp1(float z) {
  return fmaxf(z, 0.f) + __logf(1.f + __expf(-fabsf(z)));
}
__device__ __forceinline__ void sp_sig(float z, float& hs, float& sg) {
  float e = __expf(-fabsf(z));
  float d = __builtin_amdgcn_rcpf(1.f + e);
  hs = fmaxf(z, 0.f) + __logf(1.f + e);
  sg = (z >= 0.f ? 1.f : e) * d;
}
// h = softplus(z) >= 0  =>  sigmoid(z) = 1 - exp(-h)
__device__ __forceinline__ float sig_h(float h) { return 1.f - __expf(-h); }

// block-cooperative copies into LDS (256 threads)
__device__ __forceinline__ void cpy4(float* __restrict__ dst, const float* __restrict__ src,
                                     int n4, int t) {
  const float4* s = (const float4*)src;
  float4* d = (float4*)dst;
  for (int i = t; i < n4; i += 256) d[i] = s[i];
}
__device__ __forceinline__ void cpys(float* __restrict__ dst, const float* __restrict__ src, int n,
                                     int t) {
  for (int i = t; i < n; i += 256) dst[i] = src[i];
}

// m-role layer, FUSED single-pass: reads each weight row once, computes
// both the value dot (zh, with hin) and tangent dot (zt, with tin).
//   hout_j = softplus(zh_j) ; tout_j = zt_j * sigmoid(zh_j)
__device__ __forceinline__ void m_layer_f(const float* __restrict__ Wb,
                                          const float* __restrict__ bh,
                                          const float* __restrict__ hin,
                                          const float* __restrict__ tin, float* __restrict__ hout,
                                          float* __restrict__ tout) {
#pragma unroll
  for (int j = 0; j < 32; j++) {
    const float* r = Wb + j * 32;
    float zh = bh[j], zt = 0.f;
#pragma unroll
    for (int k = 0; k < 32; k++) {
      zh += hin[k] * r[k];
      zt += tin[k] * r[k];
    }
    float hs, sg;
    sp_sig(zh, hs, sg);
    hout[j] = hs;
    tout[j] = zt * sg;
  }
}

// m-role layer, two-pass (fallback kernel only)
__device__ __forceinline__ void m_layer(const float* __restrict__ Wb, const float* __restrict__ bh,
                                        float* __restrict__ h, const float* __restrict__ tin,
                                        float* __restrict__ tout) {
#pragma unroll
  for (int j = 0; j < 32; j++) {
    const float* r = Wb + j * 32;
    float z = bh[j];
#pragma unroll
    for (int k = 0; k < 32; k++) z += h[k] * r[k];
    tout[j] = z;
  }
#pragma unroll
  for (int j = 0; j < 32; j++) {
    const float* r = Wb + j * 32;
    float z = 0.f;
#pragma unroll
    for (int k = 0; k < 32; k++) z += tin[k] * r[k];
    float hs, sg;
    sp_sig(tout[j], hs, sg);
    h[j] = hs;
    tout[j] = z * sg;
  }
}

// plain forward layer: hout = softplus(hin @ Wt + b)
__device__ __forceinline__ void fwd_layer(const float* __restrict__ Wb,
                                          const float* __restrict__ bh,
                                          const float* __restrict__ hin, float* __restrict__ hout) {
#pragma unroll
  for (int j = 0; j < 32; j++) {
    const float* r = Wb + j * 32;
    float z = bh[j];
#pragma unroll
    for (int k = 0; k < 32; k++) z += hin[k] * r[k];
    hout[j] = sp1(z);
  }
}

// backward matvec vs ORIGINAL-layout Wh rows: gout[k] = sum_j Wh[k][j] * gin[j]
// (pointer may be GLOBAL: wave-uniform addresses -> scalar s_load stream)
__device__ __forceinline__ void bwd_mv(const float* __restrict__ Worig,
                                       const float* __restrict__ gin, float* __restrict__ gout) {
#pragma unroll
  for (int k = 0; k < 32; k++) {
    const float* r = Worig + k * 32;
    float s = 0.f;
#pragma unroll
    for (int j = 0; j < 32; j++) s += r[j] * gin[j];
    gout[k] = s;
  }
}

__global__ __launch_bounds__(256, 1) void roles3_lds_kernel(
    const float* __restrict__ in, const float* __restrict__ ws, const float* __restrict__ m_b0,
    const float* __restrict__ m_bh, const float* __restrict__ m_bo, const float* __restrict__ u_W0,
    const float* __restrict__ u_b0, const float* __restrict__ u_Wh, const float* __restrict__ u_bh,
    const float* __restrict__ u_Wo, const float* __restrict__ d_b0, const float* __restrict__ d_bh,
    const float* __restrict__ d_bo, float* __restrict__ sc, int B) {
  __shared__ __align__(16) float W[LDS_FLOATS];
  const int role = blockIdx.x % 3;
  const int t = threadIdx.x;

  // ---- stage role weights + biases into LDS ----
  if (role == 0) {
    cpy4(W, ws + MW0T, 48, t);
    cpy4(W + 192, ws + MWHT, 1024, t);
    cpy4(W + 4288, ws + MWOT, 288, t);
    cpys(W + 5440, m_b0, 32, t);
    cpys(W + 5472, m_bh, 128, t);
    cpys(W + 5600, m_bo, 36, t);
  } else if (role == 1) {
    cpy4(W, ws + UW0T, 48, t);
    cpy4(W + 192, ws + UWHT, 1024, t);
    cpy4(W + 4288, u_Wo, 8, t);
    cpy4(W + 4320, u_W0, 48, t);  // original layout for final grad
    cpys(W + 4512, u_b0, 32, t);
    cpys(W + 4544, u_bh, 128, t);
  } else {
    cpy4(W, ws + DW0T, 48, t);
    cpy4(W + 192, ws + DWHT, 1024, t);
    cpy4(W + 4288, ws + DWOT, 288, t);
    cpys(W + 5440, d_b0, 32, t);
    cpys(W + 5472, d_bh, 128, t);
    cpys(W + 5600, d_bo, 36, t);
  }
  __syncthreads();

  const int e = (blockIdx.x / 3) * 256 + t;
  if (e >= B) return;
  const float* ip = in + (long)e * 18;
  const long Bl = B;

  float x[6];
#pragma unroll
  for (int i = 0; i < 6; i++) x[i] = ip[i];

  if (role == 0) {
    // ================= m: fwd + JVP (fused layers) =================
    const float* w0 = W;
    const float* wh = W + 192;
    const float* wo = W + 4288;
    const float* b0 = W + 5440;
    const float* bh = W + 5472;
    const float* bo = W + 5600;
    float xd[6];
#pragma unroll
    for (int i = 0; i < 6; i++) xd[i] = ip[6 + i];
    float h[32], tv[32], h2[32], t2[32];
#pragma unroll
    for (int j = 0; j < 32; j++) {
      const float* r = w0 + j * 6;
      float zh = b0[j], zt = 0.f;
#pragma unroll
      for (int k = 0; k < 6; k++) {
        zh += x[k] * r[k];
        zt += xd[k] * r[k];
      }
      float hs, sg;
      sp_sig(zh, hs, sg);
      h[j] = hs;
      tv[j] = zt * sg;
    }
    m_layer_f(wh + 0 * 1024, bh + 0, h, tv, h2, t2);
    m_layer_f(wh + 1 * 1024, bh + 32, h2, t2, h, tv);
    m_layer_f(wh + 2 * 1024, bh + 64, h, tv, h2, t2);
    m_layer_f(wh + 3 * 1024, bh + 96, h2, t2, h, tv);
    // symmetrized output, pairwise
    float Ms[21], tc[6] = {0, 0, 0, 0, 0, 0};
    int idx = 0;
#pragma unroll
    for (int i = 0; i < 6; i++)
#pragma unroll
      for (int j = i; j < 6; j++) {
        const float* r = wo + (i * 6 + j) * 32;
        float v = bo[i * 6 + j], w = 0.f;
#pragma unroll
        for (int k = 0; k < 32; k++) {
          v += h[k] * r[k];
          w += tv[k] * r[k];
        }
        if (i != j) {
          const float* r2 = wo + (j * 6 + i) * 32;
          float v2 = bo[j * 6 + i], w2 = 0.f;
#pragma unroll
          for (int k = 0; k < 32; k++) {
            v2 += h[k] * r2[k];
            w2 += tv[k] * r2[k];
          }
          v = 0.5f * (v + v2);
          w = 0.5f * (w + w2);
        }
        Ms[idx] = v;
        tc[i] += w * xd[j];
        if (j != i) tc[j] += w * xd[i];
        idx++;
      }
#pragma unroll
    for (int f = 0; f < 21; f++) sc[f * Bl + e] = Ms[f];
#pragma unroll
    for (int i = 0; i < 6; i++) sc[(21 + i) * Bl + e] = tc[i];
  } else if (role == 1) {
    // ================= u: fwd + checkpointed bwd =================
    const float* w0 = W;
    const float* wh = W + 192;  // transposed (fwd)
    const float* uwo = W + 4288;
    const float* uw0O = W + 4320;
    const float* b0 = W + 4512;
    const float* bh = W + 4544;
    float hb[32], hd[32], s[32], r2[32];
    // ha -> s
#pragma unroll
    for (int j = 0; j < 32; j++) {
      const float* r = w0 + j * 6;
      float z = b0[j];
#pragma unroll
      for (int k = 0; k < 6; k++) z += x[k] * r[k];
      s[j] = sp1(z);
    }
    fwd_layer(wh + 0 * 1024, bh + 0, s, hb);   // hb (checkpoint)
    fwd_layer(wh + 1 * 1024, bh + 32, hb, s);  // hc (dropped, recomputed later)
    fwd_layer(wh + 2 * 1024, bh + 64, s, hd);  // hd (checkpoint)
    fwd_layer(wh + 3 * 1024, bh + 96, hd, s);  // he
    // g = Wo * sig(he), in place in s
#pragma unroll
    for (int j = 0; j < 32; j++) s[j] = uwo[j] * sig_h(s[j]);
    bwd_mv(u_Wh + 3 * 1024, s, r2);  // GLOBAL scalar path
#pragma unroll
    for (int j = 0; j < 32; j++) s[j] = r2[j] * sig_h(hd[j]);  // hd dead
    bwd_mv(u_Wh + 2 * 1024, s, hd);                            // gn -> hd
    fwd_layer(wh + 1 * 1024, bh + 32, hb, s);                  // recompute hc -> s
#pragma unroll
    for (int j = 0; j < 32; j++) r2[j] = hd[j] * sig_h(s[j]);
    bwd_mv(u_Wh + 1 * 1024, r2, s);
#pragma unroll
    for (int j = 0; j < 32; j++) r2[j] = s[j] * sig_h(hb[j]);  // hb dead
    bwd_mv(u_Wh + 0 * 1024, r2, hb);
    // recompute ha -> s
#pragma unroll
    for (int j = 0; j < 32; j++) {
      const float* r = w0 + j * 6;
      float z = b0[j];
#pragma unroll
      for (int k = 0; k < 6; k++) z += x[k] * r[k];
      s[j] = sp1(z);
    }
#pragma unroll
    for (int j = 0; j < 32; j++) s[j] = hb[j] * sig_h(s[j]);
#pragma unroll
    for (int i = 0; i < 6; i++) {
      const float* r = uw0O + i * 32;  // original layout: row i over j
      float tp = 0.f;
#pragma unroll
      for (int j = 0; j < 32; j++) tp += r[j] * s[j];
      sc[(27 + i) * Bl + e] = tp;
    }
  } else {
    // ================= d: fwd =================
    const float* w0 = W;
    const float* wh = W + 192;
    const float* wo = W + 4288;
    const float* b0 = W + 5440;
    const float* bh = W + 5472;
    const float* bo = W + 5600;
    float xd[6];
#pragma unroll
    for (int i = 0; i < 6; i++) xd[i] = ip[6 + i];
    float h[32], zn[32];
#pragma unroll
    for (int j = 0; j < 32; j++) {
      const float* r = w0 + j * 6;
      float z = b0[j];
#pragma unroll
      for (int k = 0; k < 6; k++) z += x[k] * r[k];
      h[j] = sp1(z);
    }
    fwd_layer(wh + 0 * 1024, bh + 0, h, zn);
    fwd_layer(wh + 1 * 1024, bh + 32, zn, h);
    fwd_layer(wh + 2 * 1024, bh + 64, h, zn);
    fwd_layer(wh + 3 * 1024, bh + 96, zn, h);
    float td[6] = {0, 0, 0, 0, 0, 0};
#pragma unroll
    for (int o = 0; o < 36; o++) {
      const float* r = wo + o * 32;
      float v = bo[o];
#pragma unroll
      for (int k = 0; k < 32; k++) v += h[k] * r[k];
      td[o / 6] += v * xd[o % 6];
    }
#pragma unroll
    for (int i = 0; i < 6; i++) sc[(33 + i) * Bl + e] = td[i];
  }
}

// ---------------- combine + solve ----------------
__global__ __launch_bounds__(256) void combine_kernel(const float* __restrict__ in,
                                                      const float* __restrict__ A,
                                                      const float* __restrict__ sc,
                                                      float* __restrict__ out, int B) {
  int b = blockIdx.x * 256 + threadIdx.x;
  if (b >= B) return;
  const long Bl = B;
  const float* ip = in + (long)b * 18;
  float te[6];
  {
    float tv[6];
#pragma unroll
    for (int i = 0; i < 6; i++) tv[i] = ip[12 + i];
#pragma unroll
    for (int i = 0; i < 6; i++) {
      float s = 0.f;
#pragma unroll
      for (int j = 0; j < 6; j++) s += tv[j] * A[j * 6 + i];
      te[i] = s;
    }
  }
  float Ms[6][6], r[6], y[6];
  {
    int idx = 0;
#pragma unroll
    for (int i = 0; i < 6; i++)
#pragma unroll
      for (int j = i; j < 6; j++) {
        float v = sc[idx * Bl + b];
        Ms[i][j] = v;
        Ms[j][i] = v;
        idx++;
      }
  }
#pragma unroll
  for (int i = 0; i < 6; i++)
    r[i] = te[i] - sc[(21 + i) * Bl + b] - sc[(27 + i) * Bl + b] - sc[(33 + i) * Bl + b];

#pragma unroll
  for (int k = 0; k < 6; k++) {
#pragma unroll
    for (int rr = k + 1; rr < 6; rr++) {
      bool c = fabsf(Ms[rr][k]) > fabsf(Ms[k][k]);
#pragma unroll
      for (int j = 0; j < 6; j++) {
        float a = Ms[k][j], bb = Ms[rr][j];
        Ms[k][j] = c ? bb : a;
        Ms[rr][j] = c ? a : bb;
      }
      float a = r[k], bb = r[rr];
      r[k] = c ? bb : a;
      r[rr] = c ? a : bb;
    }
    float piv = Ms[k][k];
#pragma unroll
    for (int rr = k + 1; rr < 6; rr++) {
      float f = Ms[rr][k] / piv;
#pragma unroll
      for (int j = k; j < 6; j++) Ms[rr][j] -= f * Ms[k][j];
      r[rr] -= f * r[k];
    }
  }
#pragma unroll
  for (int ki = 5; ki >= 0; ki--) {
    float v = r[ki];
#pragma unroll
    for (int j = ki + 1; j < 6; j++) v -= Ms[ki][j] * y[j];
    y[ki] = v / Ms[ki][ki];
  }
  float* op = out + (long)b * 6;
#pragma unroll
  for (int i = 0; i < 6; i++) op[i] = y[i];
}

// ---------------- fallback monolithic kernel (used only if ws too small) ----------------
__global__ __launch_bounds__(64, 1) void lnn_kernel(
    const float* __restrict__ in, const float* __restrict__ A, const float* __restrict__ ws,
    const float* __restrict__ m_b0, const float* __restrict__ m_bh, const float* __restrict__ m_bo,
    const float* __restrict__ u_W0, const float* __restrict__ u_b0, const float* __restrict__ u_Wh,
    const float* __restrict__ u_bh, const float* __restrict__ u_Wo,
    const float* __restrict__ d_b0, const float* __restrict__ d_bh, const float* __restrict__ d_bo,
    float* __restrict__ out, int B) {
  int b = blockIdx.x * 64 + threadIdx.x;
  if (b >= B) return;
  const float* ip = in + (long)b * 18;
  float x[6], xd[6], te[6];
#pragma unroll
  for (int i = 0; i < 6; i++) {
    x[i] = ip[i];
    xd[i] = ip[6 + i];
  }
  {
    float tv[6];
#pragma unroll
    for (int i = 0; i < 6; i++) tv[i] = ip[12 + i];
#pragma unroll
    for (int i = 0; i < 6; i++) {
      float s = 0.f;
#pragma unroll
      for (int j = 0; j < 6; j++) s += tv[j] * A[j * 6 + i];
      te[i] = s;
    }
  }
  float td[6] = {0, 0, 0, 0, 0, 0};
  {
    float h[32], zn[32];
    const float* w0 = ws + DW0T;
#pragma unroll
    for (int j = 0; j < 32; j++) {
      float z = d_b0[j];
#pragma unroll
      for (int k = 0; k < 6; k++) z += x[k] * w0[j * 6 + k];
      h[j] = sp1(z);
    }
    fwd_layer(ws + DWHT + 0 * 1024, d_bh + 0, h, zn);
    fwd_layer(ws + DWHT + 1 * 1024, d_bh + 32, zn, h);
    fwd_layer(ws + DWHT + 2 * 1024, d_bh + 64, h, zn);
    fwd_layer(ws + DWHT + 3 * 1024, d_bh + 96, zn, h);
    const float* wo = ws + DWOT;
#pragma unroll
    for (int o = 0; o < 36; o++) {
      float v = d_bo[o];
#pragma unroll
      for (int k = 0; k < 32; k++) v += h[k] * wo[o * 32 + k];
      td[o / 6] += v * xd[o % 6];
    }
  }
  float tp[6] = {0, 0, 0, 0, 0, 0};
  {
    float hb[32], hd[32], s[32], r2[32];
    const float* w0 = ws + UW0T;
#pragma unroll
    for (int j = 0; j < 32; j++) {
      float z = u_b0[j];
#pragma unroll
      for (int k = 0; k < 6; k++) z += x[k] * w0[j * 6 + k];
      s[j] = sp1(z);
    }
    fwd_layer(ws + UWHT + 0 * 1024, u_bh + 0, s, hb);
    fwd_layer(ws + UWHT + 1 * 1024, u_bh + 32, hb, s);
    fwd_layer(ws + UWHT + 2 * 1024, u_bh + 64, s, hd);
    fwd_layer(ws + UWHT + 3 * 1024, u_bh + 96, hd, s);
#pragma unroll
    for (int j = 0; j < 32; j++) s[j] = u_Wo[j] * sig_h(s[j]);
    bwd_mv(u_Wh + 3 * 1024, s, r2);
#pragma unroll
    for (int j = 0; j < 32; j++) s[j] = r2[j] * sig_h(hd[j]);
    bwd_mv(u_Wh + 2 * 1024, s, hd);
    fwd_layer(ws + UWHT + 1 * 1024, u_bh + 32, hb, s);
#pragma unroll
    for (int j = 0; j < 32; j++) r2[j] = hd[j] * sig_h(s[j]);
    bwd_mv(u_Wh + 1 * 1024, r2, s);
#pragma unroll
    for (int j = 0; j < 32; j++) r2[j] = s[j] * sig_h(hb[j]);
    bwd_mv(u_Wh + 0 * 1024, r2, hb);
#pragma unroll
    for (int j = 0; j < 32; j++) {
      float z = u_b0[j];
#pragma unroll
      for (int k = 0; k < 6; k++) z += x[k] * w0[j * 6 + k];
      s[j] = sp1(z);
    }
#pragma unroll
    for (int j = 0; j < 32; j++) s[j] = hb[j] * sig_h(s[j]);
#pragma unroll
    for (int i = 0; i < 6; i++) {
      float t = 0.f;
#pragma unroll
      for (int j = 0; j < 32; j++) t += u_W0[i * 32 + j] * s[j];
      tp[i] = t;
    }
  }
  float Ms[6][6], tc[6];
  {
    float h[32], t[32], zn[32];
    const float* w0 = ws + MW0T;
#pragma unroll
    for (int j = 0; j < 32; j++) {
      float zh = m_b0[j], zt = 0.f;
#pragma unroll
      for (int k = 0; k < 6; k++) {
        zh += x[k] * w0[j * 6 + k];
        zt += xd[k] * w0[j * 6 + k];
      }
      float hs, sg;
      sp_sig(zh, hs, sg);
      h[j] = hs;
      t[j] = zt * sg;
    }
    m_layer(ws + MWHT + 0 * 1024, m_bh + 0, h, t, zn);
    m_layer(ws + MWHT + 1 * 1024, m_bh + 32, h, zn, t);
    m_layer(ws + MWHT + 2 * 1024, m_bh + 64, h, t, zn);
    m_layer(ws + MWHT + 3 * 1024, m_bh + 96, h, zn, t);
    const float* wo = ws + MWOT;
    float Msv[21];
    int idx = 0;
#pragma unroll
    for (int i = 0; i < 6; i++) tc[i] = 0.f;
#pragma unroll
    for (int i = 0; i < 6; i++)
#pragma unroll
      for (int j = i; j < 6; j++) {
        const float* r = wo + (i * 6 + j) * 32;
        float v = m_bo[i * 6 + j], w = 0.f;
#pragma unroll
        for (int k = 0; k < 32; k++) {
          v += h[k] * r[k];
          w += t[k] * r[k];
        }
        if (i != j) {
          const float* rr = wo + (j * 6 + i) * 32;
          float v2 = m_bo[j * 6 + i], w2 = 0.f;
#pragma unroll
          for (int k = 0; k < 32; k++) {
            v2 += h[k] * rr[k];
            w2 += t[k] * rr[k];
          }
          v = 0.5f * (v + v2);
          w = 0.5f * (w + w2);
        }
        Msv[idx] = v;
        tc[i] += w * xd[j];
        if (j != i) tc[j] += w * xd[i];
        idx++;
      }
    idx = 0;
#pragma unroll
    for (int i = 0; i < 6; i++)
#pragma unroll
      for (int j = i; j < 6; j++) {
        Ms[i][j] = Msv[idx];
        Ms[j][i] = Msv[idx];
        idx++;
      }
  }
  float r[6], y[6];
#pragma unroll
  for (int i = 0; i < 6; i++) r[i] = te[i] - tc[i] - tp[i] - td[i];
#pragma unroll
  for (int k = 0; k < 6; k++) {
#pragma unroll
    for (int rr = k + 1; rr < 6; rr++) {
      bool c = fabsf(Ms[rr][k]) > fabsf(Ms[k][k]);
#pragma unroll
      for (int j = 0; j < 6; j++) {
        float a = Ms[k][j], bb = Ms[rr][j];
        Ms[k][j] = c ? bb : a;
        Ms[rr][j] = c ? a : bb;
      }
      float a = r[k], bb = r[rr];
      r[k] = c ? bb : a;
      r[rr] = c ? a : bb;
    }
    float piv = Ms[k][k];
#pragma unroll
    for (int rr = k + 1; rr < 6; rr++) {
      float f = Ms[rr][k] / piv;
#pragma unroll
      for (int j = k; j < 6; j++) Ms[rr][j] -= f * Ms[k][j];
      r[rr] -= f * r[k];
    }
  }
#pragma unroll
  for (int ki = 5; ki >= 0; ki--) {
    float v = r[ki];
#pragma unroll
    for (int j = ki + 1; j < 6; j++) v -= Ms[ki][j] * y[j];
    y[ki] = v / Ms[ki][ki];
  }
  float* op = out + (long)b * 6;
#pragma unroll
  for (int i = 0; i < 6; i++) op[i] = y[i];
}

extern "C" void kernel_launch(void* const* d_in, const int* in_sizes, int n_in, void* d_out,
                              int out_size, void* d_ws, size_t ws_size, hipStream_t stream) {
  const float* inputs = (const float*)d_in[0];
  const float* A = (const float*)d_in[1];
  const float* m_W0 = (const float*)d_in[2];
  const float* m_b0 = (const float*)d_in[3];
  const float* m_Wh = (const float*)d_in[4];
  const float* m_bh = (const float*)d_in[5];
  const float* m_Wo = (const float*)d_in[6];
  const float* m_bo = (const float*)d_in[7];
  const float* u_W0 = (const float*)d_in[8];
  const float* u_b0 = (const float*)d_in[9];
  const float* u_Wh = (const float*)d_in[10];
  const float* u_bh = (const float*)d_in[11];
  const float* u_Wo = (const float*)d_in[12];
  const float* d_W0 = (const float*)d_in[14];
  const float* d_b0 = (const float*)d_in[15];
  const float* d_Wh = (const float*)d_in[16];
  const float* d_bh = (const float*)d_in[17];
  const float* d_Wo = (const float*)d_in[18];
  const float* d_bo = (const float*)d_in[19];

  float* ws = (float*)d_ws;
  float* out = (float*)d_out;
  int B = in_sizes[0] / 18;

  prep_kernel<<<16, 256, 0, stream>>>(m_W0, m_Wh, m_Wo, u_W0, u_Wh, u_Wo, d_W0, d_Wh, d_Wo, ws);

  size_t need = (size_t)(SC_BASE + (size_t)B * 39) * 4;
  if (ws_size >= need) {
    float* sc = ws + SC_BASE;
    int nb = (B + 255) / 256;
    roles3_lds_kernel<<<3 * nb, 256, 0, stream>>>(inputs, ws, m_b0, m_bh, m_bo, u_W0, u_b0, u_Wh,
                                                  u_bh, u_Wo, d_b0, d_bh, d_bo, sc, B);
    combine_kernel<<<(B + 255) / 256, 256, 0, stream>>>(inputs, A, sc, out, B);
  } else {
    lnn_kernel<<<(B + 63) / 64, 64, 0, stream>>>(inputs, A, ws, m_b0, m_bh, m_bo, u_W0, u_b0, u_Wh,
                                                 u_bh, u_Wo, d_b0, d_bh, d_bo, out, B);
  }
}

// Round 6
// 149.641 us; speedup vs baseline: 1.8993x; 1.0530x over previous
//
#include <hip/hip_runtime.h>

// LnnDynamics v7: 4-lane cooperative groups + LDS activations.
// v6 falsified the LDS-throughput theory (halving LDS reads: no change).
// Remaining stalls: serial 32-FMA dependent chains (50% duty cap), 2
// waves/SIMD (VGPR 208), ~300KB unrolled I-stream. All three stem from
// per-thread register-array activations forcing full unroll.
// v7: 4 lanes/element (q=tid&3), activations in LDS (stride-36 rows,
// conflict-free), lane owns outputs j=q+4m -> j-loops and layer-loops
// ROLL (outputs are memory) -> code ~10KB, VGPR ~120, 4x grid, balanced
// 32-FMA chains per accumulator. Weight rows restrided to 36 floats in
// LDS so the quad's 4 concurrent broadcasts hit distinct bank clusters.
// tc via LDS float atomics (intra-wave only; quads never cross waves ->
// no barriers after the staging barrier).
// sc layout UNCHANGED (39 fields): 0-20 Ms, 21-26 tc, 27-32 tp, 33-38 td.

#define NQ 6
#define HID 32
#define NHID 4  // NL-1

// workspace float offsets (built by prep_kernel)
#define MW0T 0
#define UW0T 192
#define DW0T 384
#define MWHT 576
#define UWHT (576 + 4096)
#define DWHT (576 + 8192)
#define MWOT (576 + 12288)
#define DWOT (MWOT + 1152)
#define UWOT (DWOT + 1152)
// v7 additions (old layout ends at 15232)
#define W0P_M 15200  // overlaps UWOT+32.. no: UWOT ends 15232 -> see note
#define W0P_U 15488
#define W0P_D 15744
#define WSYM 16000  // 21*32 = 672 -> 16672
#define BSYM 16672  // 21 -> 16693
#define SC_BASE 16896  // per-element scratch starts here (floats)
// note: UWOT = 14016+1152 = 15168, +32 -> ends 15200. W0P_M at 15200 ok.

// ---- LDS layout (floats), single shared array ----
#define L_W0P 0  // 256 (stride-8 padded rows)
#define L_WHT 256  // 128 rows * 36 = 4608 -> 4864  (fwd/transposed)
// m:
#define LM_WSYM 4864  // 21*36 = 756 -> 5620
#define LM_BSYM 5620  // 21
#define LM_B0 5644    // 32
#define LM_BH 5676    // 128 -> 5804
#define LM_AH 5804    // 64*36 = 2304 -> 8108
#define LM_AT 8108    // 2304 -> 10412
#define LM_XD 10412   // 64*6 = 384 -> 10796
#define LM_TC 10796   // 384 -> 11180
// u:
#define LU_WHO 4864  // 4608 -> 9472 (orig-layout Wh, restrided)
#define LU_WO 9472   // 32
#define LU_W0O 9504  // 6*36 = 216 -> 9720
#define LU_B0 9720   // 32
#define LU_BH 9752   // 128 -> 9880
#define LU_S 9880    // 2304 -> 12184
#define LU_HB 12184  // 2304 -> 14488
#define LU_HD 14488  // 2304 -> 16792
// d:
#define LD_WOT 4864  // 36*36 = 1296 -> 6160
#define LD_B0 6160   // 32
#define LD_BH 6192   // 128 -> 6320
#define LD_BO 6320   // 36 -> 6356
#define LD_S 6356    // 2304 -> 8660
#define LDS_TOT 16792  // 67168 B -> 2 blocks/CU

__device__ const int IU21[21] = {0, 0, 0, 0, 0, 0, 1, 1, 1, 1, 1, 2, 2, 2, 2, 3, 3, 3, 4, 4, 5};
__device__ const int JU21[21] = {0, 1, 2, 3, 4, 5, 1, 2, 3, 4, 5, 2, 3, 4, 5, 3, 4, 5, 4, 5, 5};

__global__ void prep_kernel(const float* __restrict__ mW0, const float* __restrict__ mWh,
                            const float* __restrict__ mWo, const float* __restrict__ m_bo,
                            const float* __restrict__ uW0, const float* __restrict__ uWh,
                            const float* __restrict__ uWo, const float* __restrict__ dW0,
                            const float* __restrict__ dWh, const float* __restrict__ dWo,
                            float* __restrict__ ws) {
  int t = blockIdx.x * blockDim.x + threadIdx.x;
  if (t < 192) {  // W0t[j*6+k] = W0[k*32+j]  (fallback layout)
    int j = t / 6, k = t % 6;
    ws[MW0T + t] = mW0[k * HID + j];
    ws[UW0T + t] = uW0[k * HID + j];
    ws[DW0T + t] = dW0[k * HID + j];
  }
  if (t < 256) {  // padded W0p[j*8+k] = W0[k*32+j], k<6
    int j = t >> 3, k = t & 7;
    float vm = 0.f, vu = 0.f, vd = 0.f;
    if (k < 6) {
      vm = mW0[k * HID + j];
      vu = uW0[k * HID + j];
      vd = dW0[k * HID + j];
    }
    ws[W0P_M + t] = vm;
    ws[W0P_U + t] = vu;
    ws[W0P_D + t] = vd;
  }
  if (t < 4096) {  // Wht[(l*32+j)*32+k] = Wh[(l*32+k)*32+j]
    int l = t >> 10, j = (t >> 5) & 31, k = t & 31;
    int src = l * 1024 + k * 32 + j;
    ws[MWHT + t] = mWh[src];
    ws[UWHT + t] = uWh[src];
    ws[DWHT + t] = dWh[src];
  }
  if (t < 1152) {  // Wot[o*32+k] = Wo[k*36+o]
    int o = t / 32, k = t % 32;
    ws[MWOT + t] = mWo[k * 36 + o];
    ws[DWOT + t] = dWo[k * 36 + o];
  }
  if (t < 32) ws[UWOT + t] = uWo[t];
  if (t < 672) {  // symmetrized m output weights: rows p (21) of 32
    int p = t >> 5, k = t & 31;
    int i = IU21[p], j = JU21[p];
    ws[WSYM + t] = 0.5f * (mWo[k * 36 + i * 6 + j] + mWo[k * 36 + j * 6 + i]);
  }
  if (t < 21) {
    int i = IU21[t], j = JU21[t];
    ws[BSYM + t] = 0.5f * (m_bo[i * 6 + j] + m_bo[j * 6 + i]);
  }
}

__device__ __forceinline__ float sp1(float z) {
  return fmaxf(z, 0.f) + __logf(1.f + __expf(-fabsf(z)));
}
__device__ __forceinline__ void sp_sig(float z, float& hs, float& sg) {
  float e = __expf(-fabsf(z));
  float d = __builtin_amdgcn_rcpf(1.f + e);
  hs = fmaxf(z, 0.f) + __logf(1.f + e);
  sg = (z >= 0.f ? 1.f : e) * d;
}
__device__ __forceinline__ float sig_h(float h) { return 1.f - __expf(-h); }

__device__ __forceinline__ void cpy4(float* __restrict__ dst, const float* __restrict__ src,
                                     int n4, int t) {
  const float4* s = (const float4*)src;
  float4* d = (float4*)dst;
  for (int i = t; i < n4; i += 256) d[i] = s[i];
}
__device__ __forceinline__ void cpys(float* __restrict__ dst, const float* __restrict__ src, int n,
                                     int t) {
  for (int i = t; i < n; i += 256) dst[i] = src[i];
}
// copy nrows x 32 (row-major) into stride-36 LDS rows
__device__ __forceinline__ void stage36(float* __restrict__ dst, const float* __restrict__ src,
                                        int nrows, int t) {
  int n4 = nrows * 8;
  for (int i = t; i < n4; i += 256) {
    int r = i >> 3, c = i & 7;
    *(float4*)&dst[r * 36 + c * 4] = *(const float4*)&src[r * 32 + c * 4];
  }
}

// load 32 contiguous floats from LDS into registers (static indexing)
__device__ __forceinline__ void load32(const float* p, float* hv) {
#pragma unroll
  for (int c = 0; c < 8; c++) {
    float4 v = *(const float4*)&p[4 * c];
    hv[4 * c + 0] = v.x;
    hv[4 * c + 1] = v.y;
    hv[4 * c + 2] = v.z;
    hv[4 * c + 3] = v.w;
  }
}
__device__ __forceinline__ float dot32(const float* hv, const float* r) {
  float s = 0.f;
#pragma unroll
  for (int c = 0; c < 8; c++) {
    float4 w = *(const float4*)&r[4 * c];
    s += hv[4 * c + 0] * w.x + hv[4 * c + 1] * w.y + hv[4 * c + 2] * w.z + hv[4 * c + 3] * w.w;
  }
  return s;
}

// forward layer, src -> dst (may be same array; inputs reg-loaded first)
__device__ __forceinline__ void coopFwd(const float* Wb, const float* bh, const float* src,
                                        float* dst, int q) {
  float hv[32];
  load32(src, hv);
#pragma unroll 2
  for (int m8 = 0; m8 < 8; m8++) {
    int j = q + 4 * m8;
    float z = bh[j] + dot32(hv, Wb + j * 36);
    dst[j] = sp1(z);
  }
}
// backward matvec (no bias/act), src -> dst
__device__ __forceinline__ void coopBwd(const float* Wb, const float* src, float* dst, int q) {
  float hv[32];
  load32(src, hv);
#pragma unroll 2
  for (int m8 = 0; m8 < 8; m8++) {
    int k = q + 4 * m8;
    dst[k] = dot32(hv, Wb + k * 36);
  }
}
// fused value+tangent layer, in-place over (ah, at)
__device__ __forceinline__ void coopFused(const float* Wb, const float* bh, float* ah, float* at,
                                          int q) {
  float hv[32], tv[32];
  load32(ah, hv);
  load32(at, tv);
#pragma unroll 2
  for (int m8 = 0; m8 < 8; m8++) {
    int j = q + 4 * m8;
    const float* r = Wb + j * 36;
    float zh = bh[j], zt = 0.f;
#pragma unroll
    for (int c = 0; c < 8; c++) {
      float4 w = *(const float4*)&r[4 * c];
      zh += hv[4 * c + 0] * w.x + hv[4 * c + 1] * w.y + hv[4 * c + 2] * w.z + hv[4 * c + 3] * w.w;
      zt += tv[4 * c + 0] * w.x + tv[4 * c + 1] * w.y + tv[4 * c + 2] * w.z + tv[4 * c + 3] * w.w;
    }
    float hs, sg;
    sp_sig(zh, hs, sg);
    ah[j] = hs;
    at[j] = zt * sg;
  }
}

__global__ __launch_bounds__(256, 1) void roles3_coop(
    const float* __restrict__ in, const float* __restrict__ ws, const float* __restrict__ m_b0,
    const float* __restrict__ m_bh, const float* __restrict__ u_W0, const float* __restrict__ u_b0,
    const float* __restrict__ u_Wh, const float* __restrict__ u_bh, const float* __restrict__ u_Wo,
    const float* __restrict__ d_b0, const float* __restrict__ d_bh, const float* __restrict__ d_bo,
    float* __restrict__ sc, int B) {
  __shared__ __align__(16) float L[LDS_TOT];
  const int role = blockIdx.x % 3;
  const int t = threadIdx.x;

  // ---- stage weights (restrided to 36) ----
  if (role == 0) {
    cpy4(L + L_W0P, ws + W0P_M, 64, t);
    stage36(L + L_WHT, ws + MWHT, 128, t);
    stage36(L + LM_WSYM, ws + WSYM, 21, t);
    cpys(L + LM_BSYM, ws + BSYM, 21, t);
    cpys(L + LM_B0, m_b0, 32, t);
    cpys(L + LM_BH, m_bh, 128, t);
  } else if (role == 1) {
    cpy4(L + L_W0P, ws + W0P_U, 64, t);
    stage36(L + L_WHT, ws + UWHT, 128, t);
    stage36(L + LU_WHO, u_Wh, 128, t);
    cpy4(L + LU_WO, u_Wo, 8, t);
    stage36(L + LU_W0O, u_W0, 6, t);
    cpys(L + LU_B0, u_b0, 32, t);
    cpys(L + LU_BH, u_bh, 128, t);
  } else {
    cpy4(L + L_W0P, ws + W0P_D, 64, t);
    stage36(L + L_WHT, ws + DWHT, 128, t);
    stage36(L + LD_WOT, ws + DWOT, 36, t);
    cpys(L + LD_B0, d_b0, 32, t);
    cpys(L + LD_BH, d_bh, 128, t);
    cpys(L + LD_BO, d_bo, 36, t);
  }
  __syncthreads();

  const int el = t >> 2;   // element within block (0..63)
  const int q = t & 3;     // lane role within quad
  const int e = (blockIdx.x / 3) * 64 + el;
  if (e >= B) return;
  const float* ip = in + (long)e * 18;
  const long Bl = B;
  const int eoff = el * 36;

  float x0 = ip[0], x1 = ip[1], x2 = ip[2], x3 = ip[3], x4 = ip[4], x5 = ip[5];

  if (role == 0) {
    // ================= m: fwd + JVP =================
    float d0 = ip[6], d1 = ip[7], d2 = ip[8], d3 = ip[9], d4 = ip[10], d5 = ip[11];
    // stage xd for tc accumulation
    L[LM_XD + el * 6 + q] = ip[6 + q];
    if (q < 2) L[LM_XD + el * 6 + 4 + q] = ip[10 + q];
    float* aH = L + LM_AH + eoff;
    float* aT = L + LM_AT + eoff;
    // first layer (padded W0p rows of 8)
#pragma unroll 2
    for (int m8 = 0; m8 < 8; m8++) {
      int j = q + 4 * m8;
      float4 wa = *(const float4*)&L[L_W0P + j * 8];
      float4 wb = *(const float4*)&L[L_W0P + j * 8 + 4];
      float zh = L[LM_B0 + j] + x0 * wa.x + x1 * wa.y + x2 * wa.z + x3 * wa.w + x4 * wb.x +
                 x5 * wb.y;
      float zt = d0 * wa.x + d1 * wa.y + d2 * wa.z + d3 * wa.w + d4 * wb.x + d5 * wb.y;
      float hs, sg;
      sp_sig(zh, hs, sg);
      aH[j] = hs;
      aT[j] = zt * sg;
    }
#pragma unroll 1
    for (int l = 0; l < 4; l++)
      coopFused(L + L_WHT + l * 1152, L + LM_BH + l * 32, aH, aT, q);
    // output: symmetrized pairs
    float hv[32], tv[32];
    load32(aH, hv);
    load32(aT, tv);
    if (q == 0) {
#pragma unroll
      for (int c = 0; c < 6; c++) L[LM_TC + el * 6 + c] = 0.f;
    }
#pragma unroll 1
    for (int mm = 0; mm < 6; mm++) {
      int p = q + 4 * mm;
      if (p < 21) {
        const float* r = L + LM_WSYM + p * 36;
        float v = L[LM_BSYM + p] + dot32(hv, r);
        float w = dot32(tv, r);
        sc[(long)p * Bl + e] = v;
        int iu = IU21[p], ju = JU21[p];
        float xdj = L[LM_XD + el * 6 + ju];
        atomicAdd(&L[LM_TC + el * 6 + iu], w * xdj);
        if (iu != ju) {
          float xdi = L[LM_XD + el * 6 + iu];
          atomicAdd(&L[LM_TC + el * 6 + ju], w * xdi);
        }
      }
    }
    sc[(long)(21 + q) * Bl + e] = L[LM_TC + el * 6 + q];
    if (q < 2) sc[(long)(25 + q) * Bl + e] = L[LM_TC + el * 6 + 4 + q];
  } else if (role == 1) {
    // ================= u: fwd + checkpointed bwd =================
    float* S = L + LU_S + eoff;
    float* HB = L + LU_HB + eoff;
    float* HD = L + LU_HD + eoff;
    // ha -> S
#pragma unroll 2
    for (int m8 = 0; m8 < 8; m8++) {
      int j = q + 4 * m8;
      float4 wa = *(const float4*)&L[L_W0P + j * 8];
      float4 wb = *(const float4*)&L[L_W0P + j * 8 + 4];
      float z = L[LU_B0 + j] + x0 * wa.x + x1 * wa.y + x2 * wa.z + x3 * wa.w + x4 * wb.x +
                x5 * wb.y;
      S[j] = sp1(z);
    }
    coopFwd(L + L_WHT + 0 * 1152, L + LU_BH + 0, S, HB, q);   // hb (ckpt)
    coopFwd(L + L_WHT + 1 * 1152, L + LU_BH + 32, HB, S, q);  // hc
    coopFwd(L + L_WHT + 2 * 1152, L + LU_BH + 64, S, HD, q);  // hd (ckpt)
    coopFwd(L + L_WHT + 3 * 1152, L + LU_BH + 96, HD, S, q);  // he
    // g = Wo * sig(he)
#pragma unroll 2
    for (int m8 = 0; m8 < 8; m8++) {
      int j = q + 4 * m8;
      S[j] = L[LU_WO + j] * sig_h(S[j]);
    }
    coopBwd(L + LU_WHO + 3 * 1152, S, S, q);  // in-place OK (reg preload)
#pragma unroll 2
    for (int m8 = 0; m8 < 8; m8++) {
      int j = q + 4 * m8;
      S[j] = S[j] * sig_h(HD[j]);
    }
    coopBwd(L + LU_WHO + 2 * 1152, S, HD, q);                 // grad -> HD
    coopFwd(L + L_WHT + 1 * 1152, L + LU_BH + 32, HB, S, q);  // recompute hc
#pragma unroll 2
    for (int m8 = 0; m8 < 8; m8++) {
      int j = q + 4 * m8;
      HD[j] = HD[j] * sig_h(S[j]);
    }
    coopBwd(L + LU_WHO + 1 * 1152, HD, S, q);
#pragma unroll 2
    for (int m8 = 0; m8 < 8; m8++) {
      int j = q + 4 * m8;
      HB[j] = S[j] * sig_h(HB[j]);
    }
    coopBwd(L + LU_WHO + 0 * 1152, HB, HD, q);
    // recompute ha -> S
#pragma unroll 2
    for (int m8 = 0; m8 < 8; m8++) {
      int j = q + 4 * m8;
      float4 wa = *(const float4*)&L[L_W0P + j * 8];
      float4 wb = *(const float4*)&L[L_W0P + j * 8 + 4];
      float z = L[LU_B0 + j] + x0 * wa.x + x1 * wa.y + x2 * wa.z + x3 * wa.w + x4 * wb.x +
                x5 * wb.y;
      S[j] = sp1(z);
    }
#pragma unroll 2
    for (int m8 = 0; m8 < 8; m8++) {
      int j = q + 4 * m8;
      S[j] = HD[j] * sig_h(S[j]);
    }
    // tp_i = W0_orig row i . S
    {
      float hv[32];
      load32(S, hv);
      float tp = dot32(hv, L + LU_W0O + q * 36);
      sc[(long)(27 + q) * Bl + e] = tp;
      if (q < 2) {
        float tp2 = dot32(hv, L + LU_W0O + (q + 4) * 36);
        sc[(long)(31 + q) * Bl + e] = tp2;
      }
    }
  } else {
    // ================= d: fwd =================
    float* S = L + LD_S + eoff;
#pragma unroll 2
    for (int m8 = 0; m8 < 8; m8++) {
      int j = q + 4 * m8;
      float4 wa = *(const float4*)&L[L_W0P + j * 8];
      float4 wb = *(const float4*)&L[L_W0P + j * 8 + 4];
      float z = L[LD_B0 + j] + x0 * wa.x + x1 * wa.y + x2 * wa.z + x3 * wa.w + x4 * wb.x +
                x5 * wb.y;
      S[j] = sp1(z);
    }
#pragma unroll 1
    for (int l = 0; l < 4; l++)
      coopFwd(L + L_WHT + l * 1152, L + LD_BH + l * 32, S, S, q);
    float hv[32];
    load32(S, hv);
    {
      float td = 0.f;
#pragma unroll 1
      for (int c = 0; c < 6; c++) {
        float v = L[LD_BO + q * 6 + c] + dot32(hv, L + LD_WOT + (q * 6 + c) * 36);
        td += v * ip[6 + c];
      }
      sc[(long)(33 + q) * Bl + e] = td;
    }
    if (q < 2) {
      int i = q + 4;
      float td = 0.f;
#pragma unroll 1
      for (int c = 0; c < 6; c++) {
        float v = L[LD_BO + i * 6 + c] + dot32(hv, L + LD_WOT + (i * 6 + c) * 36);
        td += v * ip[6 + c];
      }
      sc[(long)(33 + i) * Bl + e] = td;
    }
  }
}

// ---------------- combine + solve (unchanged) ----------------
__global__ __launch_bounds__(256) void combine_kernel(const float* __restrict__ in,
                                                      const float* __restrict__ A,
                                                      const float* __restrict__ sc,
                                                      float* __restrict__ out, int B) {
  int b = blockIdx.x * 256 + threadIdx.x;
  if (b >= B) return;
  const long Bl = B;
  const float* ip = in + (long)b * 18;
  float te[6];
  {
    float tv[6];
#pragma unroll
    for (int i = 0; i < 6; i++) tv[i] = ip[12 + i];
#pragma unroll
    for (int i = 0; i < 6; i++) {
      float s = 0.f;
#pragma unroll
      for (int j = 0; j < 6; j++) s += tv[j] * A[j * 6 + i];
      te[i] = s;
    }
  }
  float Ms[6][6], r[6], y[6];
  {
    int idx = 0;
#pragma unroll
    for (int i = 0; i < 6; i++)
#pragma unroll
      for (int j = i; j < 6; j++) {
        float v = sc[idx * Bl + b];
        Ms[i][j] = v;
        Ms[j][i] = v;
        idx++;
      }
  }
#pragma unroll
  for (int i = 0; i < 6; i++)
    r[i] = te[i] - sc[(21 + i) * Bl + b] - sc[(27 + i) * Bl + b] - sc[(33 + i) * Bl + b];

#pragma unroll
  for (int k = 0; k < 6; k++) {
#pragma unroll
    for (int rr = k + 1; rr < 6; rr++) {
      bool c = fabsf(Ms[rr][k]) > fabsf(Ms[k][k]);
#pragma unroll
      for (int j = 0; j < 6; j++) {
        float a = Ms[k][j], bb = Ms[rr][j];
        Ms[k][j] = c ? bb : a;
        Ms[rr][j] = c ? a : bb;
      }
      float a = r[k], bb = r[rr];
      r[k] = c ? bb : a;
      r[rr] = c ? a : bb;
    }
    float piv = Ms[k][k];
#pragma unroll
    for (int rr = k + 1; rr < 6; rr++) {
      float f = Ms[rr][k] / piv;
#pragma unroll
      for (int j = k; j < 6; j++) Ms[rr][j] -= f * Ms[k][j];
      r[rr] -= f * r[k];
    }
  }
#pragma unroll
  for (int ki = 5; ki >= 0; ki--) {
    float v = r[ki];
#pragma unroll
    for (int j = ki + 1; j < 6; j++) v -= Ms[ki][j] * y[j];
    y[ki] = v / Ms[ki][ki];
  }
  float* op = out + (long)b * 6;
#pragma unroll
  for (int i = 0; i < 6; i++) op[i] = y[i];
}

// ---------------- fallback monolithic kernel (used only if ws too small) ----------------
__device__ __forceinline__ void fwd_layer(const float* __restrict__ Wb,
                                          const float* __restrict__ bh,
                                          const float* __restrict__ hin, float* __restrict__ hout) {
#pragma unroll
  for (int j = 0; j < 32; j++) {
    const float* r = Wb + j * 32;
    float z = bh[j];
#pragma unroll
    for (int k = 0; k < 32; k++) z += hin[k] * r[k];
    hout[j] = sp1(z);
  }
}
__device__ __forceinline__ void m_layer(const float* __restrict__ Wb, const float* __restrict__ bh,
                                        float* __restrict__ h, const float* __restrict__ tin,
                                        float* __restrict__ tout) {
#pragma unroll
  for (int j = 0; j < 32; j++) {
    const float* r = Wb + j * 32;
    float z = bh[j];
#pragma unroll
    for (int k = 0; k < 32; k++) z += h[k] * r[k];
    tout[j] = z;
  }
#pragma unroll
  for (int j = 0; j < 32; j++) {
    const float* r = Wb + j * 32;
    float z = 0.f;
#pragma unroll
    for (int k = 0; k < 32; k++) z += tin[k] * r[k];
    float hs, sg;
    sp_sig(tout[j], hs, sg);
    h[j] = hs;
    tout[j] = z * sg;
  }
}
__device__ __forceinline__ void bwd_mv(const float* __restrict__ Worig,
                                       const float* __restrict__ gin, float* __restrict__ gout) {
#pragma unroll
  for (int k = 0; k < 32; k++) {
    const float* r = Worig + k * 32;
    float s = 0.f;
#pragma unroll
    for (int j = 0; j < 32; j++) s += r[j] * gin[j];
    gout[k] = s;
  }
}

__global__ __launch_bounds__(64, 1) void lnn_kernel(
    const float* __restrict__ in, const float* __restrict__ A, const float* __restrict__ ws,
    const float* __restrict__ m_b0, const float* __restrict__ m_bh, const float* __restrict__ m_bo,
    const float* __restrict__ u_W0, const float* __restrict__ u_b0, const float* __restrict__ u_Wh,
    const float* __restrict__ u_bh, const float* __restrict__ u_Wo,
    const float* __restrict__ d_b0, const float* __restrict__ d_bh, const float* __restrict__ d_bo,
    float* __restrict__ out, int B) {
  int b = blockIdx.x * 64 + threadIdx.x;
  if (b >= B) return;
  const float* ip = in + (long)b * 18;
  float x[6], xd[6], te[6];
#pragma unroll
  for (int i = 0; i < 6; i++) {
    x[i] = ip[i];
    xd[i] = ip[6 + i];
  }
  {
    float tv[6];
#pragma unroll
    for (int i = 0; i < 6; i++) tv[i] = ip[12 + i];
#pragma unroll
    for (int i = 0; i < 6; i++) {
      float s = 0.f;
#pragma unroll
      for (int j = 0; j < 6; j++) s += tv[j] * A[j * 6 + i];
      te[i] = s;
    }
  }
  float td[6] = {0, 0, 0, 0, 0, 0};
  {
    float h[32], zn[32];
    const float* w0 = ws + DW0T;
#pragma unroll
    for (int j = 0; j < 32; j++) {
      float z = d_b0[j];
#pragma unroll
      for (int k = 0; k < 6; k++) z += x[k] * w0[j * 6 + k];
      h[j] = sp1(z);
    }
    fwd_layer(ws + DWHT + 0 * 1024, d_bh + 0, h, zn);
    fwd_layer(ws + DWHT + 1 * 1024, d_bh + 32, zn, h);
    fwd_layer(ws + DWHT + 2 * 1024, d_bh + 64, h, zn);
    fwd_layer(ws + DWHT + 3 * 1024, d_bh + 96, zn, h);
    const float* wo = ws + DWOT;
#pragma unroll
    for (int o = 0; o < 36; o++) {
      float v = d_bo[o];
#pragma unroll
      for (int k = 0; k < 32; k++) v += h[k] * wo[o * 32 + k];
      td[o / 6] += v * xd[o % 6];
    }
  }
  float tp[6] = {0, 0, 0, 0, 0, 0};
  {
    float hb[32], hd[32], s[32], r2[32];
    const float* w0 = ws + UW0T;
#pragma unroll
    for (int j = 0; j < 32; j++) {
      float z = u_b0[j];
#pragma unroll
      for (int k = 0; k < 6; k++) z += x[k] * w0[j * 6 + k];
      s[j] = sp1(z);
    }
    fwd_layer(ws + UWHT + 0 * 1024, u_bh + 0, s, hb);
    fwd_layer(ws + UWHT + 1 * 1024, u_bh + 32, hb, s);
    fwd_layer(ws + UWHT + 2 * 1024, u_bh + 64, s, hd);
    fwd_layer(ws + UWHT + 3 * 1024, u_bh + 96, hd, s);
#pragma unroll
    for (int j = 0; j < 32; j++) s[j] = u_Wo[j] * sig_h(s[j]);
    bwd_mv(u_Wh + 3 * 1024, s, r2);
#pragma unroll
    for (int j = 0; j < 32; j++) s[j] = r2[j] * sig_h(hd[j]);
    bwd_mv(u_Wh + 2 * 1024, s, hd);
    fwd_layer(ws + UWHT + 1 * 1024, u_bh + 32, hb, s);
#pragma unroll
    for (int j = 0; j < 32; j++) r2[j] = hd[j] * sig_h(s[j]);
    bwd_mv(u_Wh + 1 * 1024, r2, s);
#pragma unroll
    for (int j = 0; j < 32; j++) r2[j] = s[j] * sig_h(hb[j]);
    bwd_mv(u_Wh + 0 * 1024, r2, hb);
#pragma unroll
    for (int j = 0; j < 32; j++) {
      float z = u_b0[j];
#pragma unroll
      for (int k = 0; k < 6; k++) z += x[k] * w0[j * 6 + k];
      s[j] = sp1(z);
    }
#pragma unroll
    for (int j = 0; j < 32; j++) s[j] = hb[j] * sig_h(s[j]);
#pragma unroll
    for (int i = 0; i < 6; i++) {
      float t = 0.f;
#pragma unroll
      for (int j = 0; j < 32; j++) t += u_W0[i * 32 + j] * s[j];
      tp[i] = t;
    }
  }
  float Ms[6][6], tc[6];
  {
    float h[32], t[32], zn[32];
    const float* w0 = ws + MW0T;
#pragma unroll
    for (int j = 0; j < 32; j++) {
      float zh = m_b0[j], zt = 0.f;
#pragma unroll
      for (int k = 0; k < 6; k++) {
        zh += x[k] * w0[j * 6 + k];
        zt += xd[k] * w0[j * 6 + k];
      }
      float hs, sg;
      sp_sig(zh, hs, sg);
      h[j] = hs;
      t[j] = zt * sg;
    }
    m_layer(ws + MWHT + 0 * 1024, m_bh + 0, h, t, zn);
    m_layer(ws + MWHT + 1 * 1024, m_bh + 32, h, zn, t);
    m_layer(ws + MWHT + 2 * 1024, m_bh + 64, h, t, zn);
    m_layer(ws + MWHT + 3 * 1024, m_bh + 96, h, zn, t);
    const float* wo = ws + MWOT;
    float Msv[21];
    int idx = 0;
#pragma unroll
    for (int i = 0; i < 6; i++) tc[i] = 0.f;
#pragma unroll
    for (int i = 0; i < 6; i++)
#pragma unroll
      for (int j = i; j < 6; j++) {
        const float* r = wo + (i * 6 + j) * 32;
        float v = m_bo[i * 6 + j], w = 0.f;
#pragma unroll
        for (int k = 0; k < 32; k++) {
          v += h[k] * r[k];
          w += t[k] * r[k];
        }
        if (i != j) {
          const float* rr = wo + (j * 6 + i) * 32;
          float v2 = m_bo[j * 6 + i], w2 = 0.f;
#pragma unroll
          for (int k = 0; k < 32; k++) {
            v2 += h[k] * rr[k];
            w2 += t[k] * rr[k];
          }
          v = 0.5f * (v + v2);
          w = 0.5f * (w + w2);
        }
        Msv[idx] = v;
        tc[i] += w * xd[j];
        if (j != i) tc[j] += w * xd[i];
        idx++;
      }
    idx = 0;
#pragma unroll
    for (int i = 0; i < 6; i++)
#pragma unroll
      for (int j = i; j < 6; j++) {
        Ms[i][j] = Msv[idx];
        Ms[j][i] = Msv[idx];
        idx++;
      }
  }
  float r[6], y[6];
#pragma unroll
  for (int i = 0; i < 6; i++) r[i] = te[i] - tc[i] - tp[i] - td[i];
#pragma unroll
  for (int k = 0; k < 6; k++) {
#pragma unroll
    for (int rr = k + 1; rr < 6; rr++) {
      bool c = fabsf(Ms[rr][k]) > fabsf(Ms[k][k]);
#pragma unroll
      for (int j = 0; j < 6; j++) {
        float a = Ms[k][j], bb = Ms[rr][j];
        Ms[k][j] = c ? bb : a;
        Ms[rr][j] = c ? a : bb;
      }
      float a = r[k], bb = r[rr];
      r[k] = c ? bb : a;
      r[rr] = c ? a : bb;
    }
    float piv = Ms[k][k];
#pragma unroll
    for (int rr = k + 1; rr < 6; rr++) {
      float f = Ms[rr][k] / piv;
#pragma unroll
      for (int j = k; j < 6; j++) Ms[rr][j] -= f * Ms[k][j];
      r[rr] -= f * r[k];
    }
  }
#pragma unroll
  for (int ki = 5; ki >= 0; ki--) {
    float v = r[ki];
#pragma unroll
    for (int j = ki + 1; j < 6; j++) v -= Ms[ki][j] * y[j];
    y[ki] = v / Ms[ki][ki];
  }
  float* op = out + (long)b * 6;
#pragma unroll
  for (int i = 0; i < 6; i++) op[i] = y[i];
}

extern "C" void kernel_launch(void* const* d_in, const int* in_sizes, int n_in, void* d_out,
                              int out_size, void* d_ws, size_t ws_size, hipStream_t stream) {
  const float* inputs = (const float*)d_in[0];
  const float* A = (const float*)d_in[1];
  const float* m_W0 = (const float*)d_in[2];
  const float* m_b0 = (const float*)d_in[3];
  const float* m_Wh = (const float*)d_in[4];
  const float* m_bh = (const float*)d_in[5];
  const float* m_Wo = (const float*)d_in[6];
  const float* m_bo = (const float*)d_in[7];
  const float* u_W0 = (const float*)d_in[8];
  const float* u_b0 = (const float*)d_in[9];
  const float* u_Wh = (const float*)d_in[10];
  const float* u_bh = (const float*)d_in[11];
  const float* u_Wo = (const float*)d_in[12];
  const float* d_W0 = (const float*)d_in[14];
  const float* d_b0 = (const float*)d_in[15];
  const float* d_Wh = (const float*)d_in[16];
  const float* d_bh = (const float*)d_in[17];
  const float* d_Wo = (const float*)d_in[18];
  const float* d_bo = (const float*)d_in[19];

  float* ws = (float*)d_ws;
  float* out = (float*)d_out;
  int B = in_sizes[0] / 18;

  prep_kernel<<<16, 256, 0, stream>>>(m_W0, m_Wh, m_Wo, m_bo, u_W0, u_Wh, u_Wo, d_W0, d_Wh, d_Wo,
                                      ws);

  size_t need = (size_t)(SC_BASE + (size_t)B * 39) * 4;
  if (ws_size >= need) {
    float* sc = ws + SC_BASE;
    int nb = (B + 63) / 64;
    roles3_coop<<<3 * nb, 256, 0, stream>>>(inputs, ws, m_b0, m_bh, u_W0, u_b0, u_Wh, u_bh, u_Wo,
                                            d_b0, d_bh, d_bo, sc, B);
    combine_kernel<<<(B + 255) / 256, 256, 0, stream>>>(inputs, A, sc, out, B);
  } else {
    lnn_kernel<<<(B + 63) / 64, 64, 0, stream>>>(inputs, A, ws, m_b0, m_bh, m_bo, u_W0, u_b0, u_Wh,
                                                 u_bh, u_Wo, d_b0, d_bh, d_bo, out, B);
  }
}